// Round 1
// 16072.968 us; speedup vs baseline: 1.2535x; 1.2535x over previous
//
#include <hip/hip_runtime.h>
#include <hip/hip_fp16.h>

// GetTopic: biLSTM (B=32,S=512,W=1024,HP=512) -> fused per-utterance segment
// max -> topic softmax (T=100) -> weighted gather. Inputs fp32 (probe kept).
//
// R7 vs R6 (20.1 ms; k_lstm 2x9.0 ms, latency-bound at 17.5 us/step with all
// pipes <1% busy):
//  - Barrier made cheap: RELAXED agent poll (no buffer_inv per spin) + ONE
//    acquire fence per step; producer release = single tid0 fetch_add(RELEASE)
//    after __syncthreads (replaces 256x __threadfence = 4x buffer_wbl2 +
//    per-wave vmcnt drain on the mp atomic).
//  - mp atomicMax deferred past the release-add: its MALL round-trip overlaps
//    the next poll instead of sitting inside the fence.
//  - G software-pipelined: step t+1's G slice prefetched into registers during
//    step t's compute, removing a serial MALL/HBM latency from every step.
// MFMA split-bf16 recurrence core, LDS exchange, h ping-pong slabs unchanged.

typedef unsigned short u16;
typedef unsigned int   u32;
typedef __attribute__((ext_vector_type(8))) short short8;
typedef __attribute__((ext_vector_type(4))) float float4v;

__device__ __forceinline__ float bf2f(u16 u) { return __uint_as_float(((u32)u) << 16); }
__device__ __forceinline__ u16 f2bf(float f) {
  u32 u = __float_as_uint(f);
  u32 r = u + 0x7FFFu + ((u >> 16) & 1u);   // RNE
  return (u16)(r >> 16);
}
__device__ __forceinline__ float sigm(float x) { return 1.f / (1.f + expf(-x)); }

__device__ __forceinline__ float ldF(const void* p, size_t i, int isBF) {
  return isBF ? bf2f(((const u16*)p)[i]) : ((const float*)p)[i];
}
__device__ __forceinline__ int ldI(const void* p, int i, int is64) {
  return is64 ? (int)((const u32*)p)[(size_t)2 * i] : ((const int*)p)[i];
}

union U4S8 { uint4 u; short8 s; u16 us[8]; };

// ---------------------------------------------------------------------------
// Probe: input storage formats from raw bits (R4/R5-proven).
// flags[0]: 1 = float tensors bf16, 0 = fp32.  flags[1]: 1 = ids int64.
// ---------------------------------------------------------------------------
__global__ __launch_bounds__(256) void k_probe(
    const u32* __restrict__ X, const u32* __restrict__ U, u32* __restrict__ flags)
{
  __shared__ int cnt[2];
  if (threadIdx.x == 0) { cnt[0] = 0; cnt[1] = 0; }
  __syncthreads();
  int c0 = 0;
  for (int i = threadIdx.x; i < 1024; i += 256) {
    const u32 e = (X[i] >> 7) & 0xFFu;
    if (e >= 112u && e <= 143u) c0++;
  }
  int c1 = 0;
  {
    const u32 w = U[2 * threadIdx.x + 1];
    if (w == 0u || w == 0xFFFFFFFFu) c1++;
  }
  atomicAdd(&cnt[0], c0);
  atomicAdd(&cnt[1], c1);
  __syncthreads();
  if (threadIdx.x == 0) {
    flags[0] = (cnt[0] >= 512) ? 1u : 0u;
    flags[1] = (cnt[1] >= 128) ? 1u : 0u;
  }
}

// ---------------------------------------------------------------------------
// Phase 1 (per dir): G[s][n][b] = x @ Wih^T + (bih+bhh), fp32 (fp16 if gHalf).
// GEMM M=16384 (m=s*32+b), N=2048, K=1024. 64x64 tiles, 4x4/thread. (R5)
// ---------------------------------------------------------------------------
__global__ __launch_bounds__(256) void k_xproj(
    const void* __restrict__ X, const void* __restrict__ Wih,
    const void* __restrict__ bih, const void* __restrict__ bhh,
    void* __restrict__ Gv, const u32* __restrict__ flags, int gHalf)
{
  const int isBF = (int)flags[0];
  const int m0 = blockIdx.x * 64;
  const int n0 = blockIdx.y * 64;
  __shared__ float Asl[32][68];
  __shared__ float Bsl[32][68];
  const int tid = threadIdx.x;
  const int tx = tid & 15, ty = tid >> 4;
  const int lrow = tid >> 2;
  const int lkg  = (tid & 3) * 8;
  const int am = m0 + lrow;
  const int ab = am & 31, as_ = am >> 5;           // m = s*32 + b
  const size_t arow = ((size_t)ab * 512 + as_) * 1024;
  const size_t brow = (size_t)(n0 + lrow) * 1024;
  float acc[4][4] = {{0.f, 0.f, 0.f, 0.f}};
  for (int k0 = 0; k0 < 1024; k0 += 32) {
    float a8[8], b8[8];
    if (isBF) {
      const u16* Xh = (const u16*)X;
      const u16* Wh = (const u16*)Wih;
      uint4 va = *(const uint4*)(Xh + arow + k0 + lkg);
      uint4 vb = *(const uint4*)(Wh + brow + k0 + lkg);
      const u32 wa[4] = {va.x, va.y, va.z, va.w};
      const u32 wb[4] = {vb.x, vb.y, vb.z, vb.w};
#pragma unroll
      for (int q = 0; q < 4; ++q) {
        a8[2 * q]     = __uint_as_float(wa[q] << 16);
        a8[2 * q + 1] = __uint_as_float(wa[q] & 0xFFFF0000u);
        b8[2 * q]     = __uint_as_float(wb[q] << 16);
        b8[2 * q + 1] = __uint_as_float(wb[q] & 0xFFFF0000u);
      }
    } else {
      const float* Xf = (const float*)X;
      const float* Wf = (const float*)Wih;
      const float4 xa0 = *(const float4*)(Xf + arow + k0 + lkg);
      const float4 xa1 = *(const float4*)(Xf + arow + k0 + lkg + 4);
      const float4 xb0 = *(const float4*)(Wf + brow + k0 + lkg);
      const float4 xb1 = *(const float4*)(Wf + brow + k0 + lkg + 4);
      a8[0] = xa0.x; a8[1] = xa0.y; a8[2] = xa0.z; a8[3] = xa0.w;
      a8[4] = xa1.x; a8[5] = xa1.y; a8[6] = xa1.z; a8[7] = xa1.w;
      b8[0] = xb0.x; b8[1] = xb0.y; b8[2] = xb0.z; b8[3] = xb0.w;
      b8[4] = xb1.x; b8[5] = xb1.y; b8[6] = xb1.z; b8[7] = xb1.w;
    }
#pragma unroll
    for (int q = 0; q < 8; ++q) {
      Asl[lkg + q][lrow] = a8[q];
      Bsl[lkg + q][lrow] = b8[q];
    }
    __syncthreads();
#pragma unroll
    for (int k = 0; k < 32; ++k) {
      const float4 av = *(const float4*)&Asl[k][ty * 4];
      const float4 bv = *(const float4*)&Bsl[k][tx * 4];
      float a4[4] = {av.x, av.y, av.z, av.w};
      float b4[4] = {bv.x, bv.y, bv.z, bv.w};
#pragma unroll
      for (int i = 0; i < 4; ++i)
#pragma unroll
        for (int j = 0; j < 4; ++j)
          acc[i][j] = fmaf(a4[i], b4[j], acc[i][j]);
    }
    __syncthreads();
  }
  float bias[4];
#pragma unroll
  for (int j = 0; j < 4; ++j) {
    int n = n0 + tx * 4 + j;
    bias[j] = ldF(bih, n, isBF) + ldF(bhh, n, isBF);
  }
  const int mb = m0 + ty * 4;
  const int b0 = mb & 31, ss = mb >> 5;
#pragma unroll
  for (int j = 0; j < 4; ++j) {
    const int n = n0 + tx * 4 + j;
    const size_t off = ((size_t)ss * 2048 + n) * 32 + b0;
    if (gHalf) {
      ushort4 pk;
      pk.x = __half_as_ushort(__float2half(acc[0][j] + bias[j]));
      pk.y = __half_as_ushort(__float2half(acc[1][j] + bias[j]));
      pk.z = __half_as_ushort(__float2half(acc[2][j] + bias[j]));
      pk.w = __half_as_ushort(__float2half(acc[3][j] + bias[j]));
      *(uint2*)((u16*)Gv + off) = *(uint2*)&pk;
    } else {
      float4 pk;
      pk.x = acc[0][j] + bias[j]; pk.y = acc[1][j] + bias[j];
      pk.z = acc[2][j] + bias[j]; pk.w = acc[3][j] + bias[j];
      *(float4*)((float*)Gv + off) = pk;
    }
  }
}

// ---------------------------------------------------------------------------
// Phase 2: persistent recurrence, one launch per dir. 64 WGs x 256 threads.
// WG owns 8 hidden units = 32 gate cols; Whh resident in VGPRs as split-bf16
// MFMA fragments (3 chains hh/hl/lh ~ fp32). h exchanged through 2x32KB
// ping-pong split-bf16 slabs at the MALL coherence point.
// R7 barrier: relaxed agent poll + one acquire fence; single tid0 release-add
// publishes the step (h stores drained to L2 by __syncthreads, wbl2 once);
// mp atomicMax deferred past the release; G prefetched across the barrier.
// ---------------------------------------------------------------------------
__global__ __launch_bounds__(256) void k_lstm(
    const void* __restrict__ Gv, const void* __restrict__ Whh,
    u16* __restrict__ Hhi, u16* __restrict__ Hlo,
    float* __restrict__ mp, const void* __restrict__ uid,
    unsigned* __restrict__ ctr, int dir,
    const u32* __restrict__ flags, int gHalf)
{
  __shared__ float gl[1024];          // [col32][b32] gate preacts
  const int isBF = (int)flags[0];
  const int is64 = (int)flags[1];
  const int tid = threadIdx.x;
  const int j0 = (int)blockIdx.x * 8;
  const int lane = tid & 63;
  const int wid = tid >> 6;
  const int mt = wid & 1, nt = wid >> 1;
  const int l15 = lane & 15;
  const int quad = lane >> 4;
  const int nl = nt * 16 + l15;        // col 0..31 within WG
  const int n = ((nl >> 3) * 512) + j0 + (nl & 7);   // global gate row/col

  // B-frags: split-bf16 of Whh row n. B[n=l15][k=quad*8+j].
  short8 bhi[16], blo[16];
#pragma unroll 1
  for (int kt = 0; kt < 16; ++kt) {
    const int k0 = kt * 32 + quad * 8;
    float w[8];
    if (isBF) {
      const u16* Wh = (const u16*)Whh;
#pragma unroll
      for (int jj = 0; jj < 8; ++jj) w[jj] = bf2f(Wh[(size_t)n * 512 + k0 + jj]);
    } else {
      const float* Wf = (const float*)Whh;
      const float4 w0 = *(const float4*)(Wf + (size_t)n * 512 + k0);
      const float4 w1 = *(const float4*)(Wf + (size_t)n * 512 + k0 + 4);
      w[0] = w0.x; w[1] = w0.y; w[2] = w0.z; w[3] = w0.w;
      w[4] = w1.x; w[5] = w1.y; w[6] = w1.z; w[7] = w1.w;
    }
    U4S8 ph, pl;
#pragma unroll
    for (int jj = 0; jj < 8; ++jj) {
      const u16 hi = f2bf(w[jj]);
      const float rem = w[jj] - bf2f(hi);   // exact (Sterbenz)
      ph.us[jj] = hi; pl.us[jj] = f2bf(rem);
    }
    bhi[kt] = ph.s; blo[kt] = pl.s;
  }

  const int b_a = mt * 16 + l15;        // A row = batch
  const int cb = tid & 31;              // consumer: batch
  const int ciu = tid >> 5;             // consumer: unit 0..7
  float c = 0.f;

  // Per-thread G column offset; per-step offset = sidx*65536 + gcol.
  const size_t gcol = (size_t)n * 32 + (size_t)(mt * 16 + quad * 4);

  // Prefetch G for t=0.
  float4v gpre;
  {
    const int s0 = dir ? 511 : 0;
    const size_t goff = (size_t)s0 * 65536 + gcol;
    if (gHalf) {
      const __half* Gp = (const __half*)Gv;
      gpre.x = __half2float(Gp[goff + 0]);
      gpre.y = __half2float(Gp[goff + 1]);
      gpre.z = __half2float(Gp[goff + 2]);
      gpre.w = __half2float(Gp[goff + 3]);
    } else {
      const float4 gv = *(const float4*)((const float*)Gv + goff);
      gpre.x = gv.x; gpre.y = gv.y; gpre.z = gv.z; gpre.w = gv.w;
    }
  }

  for (int t = 0; t < 512; ++t) {
    const int sidx = dir ? (511 - t) : t;
    if (t > 0) {
      if (tid == 0) {
        const unsigned target = 64u * (unsigned)t;
        // Relaxed spin (sc1 load at the coherence point; no cache invalidate
        // per iteration), then a single acquire fence for the step.
        while (__hip_atomic_load(ctr, __ATOMIC_RELAXED, __HIP_MEMORY_SCOPE_AGENT) < target)
          __builtin_amdgcn_s_sleep(2);
        __builtin_amdgcn_fence(__ATOMIC_ACQUIRE, "agent");
      }
      __syncthreads();
    }

    // C-init from prefetched G (4 consecutive batches per lane, col n).
    float4v acc_hh = gpre;
    float4v acc_hl, acc_lh;
    acc_hl.x = 0.f; acc_hl.y = 0.f; acc_hl.z = 0.f; acc_hl.w = 0.f;
    acc_lh.x = 0.f; acc_lh.y = 0.f; acc_lh.z = 0.f; acc_lh.w = 0.f;

    if (t > 0) {
      const size_t abase = (size_t)((t - 1) & 1) * 16384 + (size_t)b_a * 512 + quad * 8;
      const u16* ah = Hhi + abase;
      const u16* al = Hlo + abase;
#pragma unroll
      for (int kt = 0; kt < 16; ++kt) {
        U4S8 va, vl;
        va.u = *(const uint4*)(ah + kt * 32);
        vl.u = *(const uint4*)(al + kt * 32);
        acc_hh = __builtin_amdgcn_mfma_f32_16x16x32_bf16(va.s, bhi[kt], acc_hh, 0, 0, 0);
        acc_hl = __builtin_amdgcn_mfma_f32_16x16x32_bf16(va.s, blo[kt], acc_hl, 0, 0, 0);
        acc_lh = __builtin_amdgcn_mfma_f32_16x16x32_bf16(vl.s, bhi[kt], acc_lh, 0, 0, 0);
      }
    }

    // Prefetch next step's G: independent of the recurrence, latency hides
    // under the LDS exchange + activation + barrier.
    if (t < 511) {
      const int sn = dir ? (510 - t) : (t + 1);
      const size_t goff = (size_t)sn * 65536 + gcol;
      if (gHalf) {
        const __half* Gp = (const __half*)Gv;
        gpre.x = __half2float(Gp[goff + 0]);
        gpre.y = __half2float(Gp[goff + 1]);
        gpre.z = __half2float(Gp[goff + 2]);
        gpre.w = __half2float(Gp[goff + 3]);
      } else {
        const float4 gv = *(const float4*)((const float*)Gv + goff);
        gpre.x = gv.x; gpre.y = gv.y; gpre.z = gv.z; gpre.w = gv.w;
      }
    }

    // exchange: D row (quad*4+r) = batch - mt*16, col l15 -> nl
    {
      const int base = nl * 32 + mt * 16 + quad * 4;
      gl[base + 0] = acc_hh.x + acc_hl.x + acc_lh.x;
      gl[base + 1] = acc_hh.y + acc_hl.y + acc_lh.y;
      gl[base + 2] = acc_hh.z + acc_hl.z + acc_lh.z;
      gl[base + 3] = acc_hh.w + acc_hl.w + acc_lh.w;
    }
    __syncthreads();

    float hval;
    int id;
    {
      const float a0 = gl[(0 * 8 + ciu) * 32 + cb];
      const float a1 = gl[(1 * 8 + ciu) * 32 + cb];
      const float a2 = gl[(2 * 8 + ciu) * 32 + cb];
      const float a3 = gl[(3 * 8 + ciu) * 32 + cb];
      const float ig = sigm(a0), fg = sigm(a1);
      const float gg = tanhf(a2), og = sigm(a3);
      c = fg * c + ig * gg;
      hval = og * tanhf(c);
      const u16 hh = f2bf(hval);
      const float rem = hval - bf2f(hh);
      const size_t so = (size_t)(t & 1) * 16384 + (size_t)cb * 512 + (j0 + ciu);
      Hhi[so] = hh;
      Hlo[so] = f2bf(rem);
      id = ldI(uid, cb * 512 + sidx, is64);
    }
    // __syncthreads drains every wave's vmcnt -> h stores are in the XCD L2;
    // the single release-add then writes back dirty L2 (one wbl2) and
    // publishes the step at the MALL.
    __syncthreads();
    if (tid == 0)
      __hip_atomic_fetch_add(ctr, 1u, __ATOMIC_RELEASE, __HIP_MEMORY_SCOPE_AGENT);
    // Deferred fused max-pool: not ordered with the h exchange; its MALL
    // round-trip overlaps the next poll. Visible to k_topic via end-of-kernel
    // release.
    if (id > 0 && hval > 0.f)
      atomicMax((int*)&mp[(size_t)(cb * 32 + (id - 1)) * 1024 + dir * 512 + (j0 + ciu)],
                __float_as_int(hval));
  }
}

// ---------------------------------------------------------------------------
// Phase 4a: topic_weights -> twT[k][t] fp32, bias -> fp32.
// ---------------------------------------------------------------------------
__global__ __launch_bounds__(256) void k_prep(
    const void* __restrict__ tw, const void* __restrict__ tb,
    float* __restrict__ twT, float* __restrict__ biasT, const u32* __restrict__ flags)
{
  const int isBF = (int)flags[0];
  const int idx = blockIdx.x * 256 + threadIdx.x;
  if (idx < 102400) {
    const int t = idx >> 10, k = idx & 1023;
    twT[k * 100 + t] = ldF(tw, idx, isBF);
  } else if (idx < 102500) {
    biasT[idx - 102400] = ldF(tb, idx - 102400, isBF);
  }
}

// ---------------------------------------------------------------------------
// Phase 4: per (b,u): logits(100) -> softmax -> emb row (fp32).
// ---------------------------------------------------------------------------
__global__ __launch_bounds__(256) void k_topic(
    const float* __restrict__ mp, const float* __restrict__ twT,
    const float* __restrict__ biasT, const void* __restrict__ table,
    float* __restrict__ emb, const u32* __restrict__ flags)
{
  const int isBF = (int)flags[0];
  const int bu = blockIdx.x;
  const int tid = threadIdx.x;
  __shared__ float lrow[1024];
  __shared__ float red[128];
  __shared__ float parr[128];
  for (int i = tid; i < 1024; i += 256) lrow[i] = mp[(size_t)bu * 1024 + i];
  __syncthreads();
  float lacc = -1e30f;
  if (tid < 100) {
    lacc = biasT[tid];
    for (int k = 0; k < 1024; ++k) lacc = fmaf(lrow[k], twT[k * 100 + tid], lacc);
  }
  if (tid < 128) red[tid] = (tid < 100) ? lacc : -1e30f;
  __syncthreads();
  for (int off = 64; off > 0; off >>= 1) {
    if (tid < off) red[tid] = fmaxf(red[tid], red[tid + off]);
    __syncthreads();
  }
  const float mxv = red[0];
  __syncthreads();
  const float e = (tid < 100) ? expf(lacc - mxv) : 0.f;
  if (tid < 128) red[tid] = e;
  __syncthreads();
  for (int off = 64; off > 0; off >>= 1) {
    if (tid < off) red[tid] += red[tid + off];
    __syncthreads();
  }
  const float inv = 1.f / red[0];
  if (tid < 128) parr[tid] = e * inv;
  __syncthreads();
#pragma unroll
  for (int r = 0; r < 4; ++r) {
    const int w = tid + 256 * r;
    float a = 0.f;
    for (int t = 0; t < 100; ++t)
      a = fmaf(parr[t], ldF(table, (size_t)t * 1024 + w, isBF), a);
    emb[(size_t)bu * 1024 + w] = a;
  }
}

// ---------------------------------------------------------------------------
// Phase 5: out = emb[b][clip(|uid|-1,0,31)][w] * {1,2,0}. Dtype by flag.
// ---------------------------------------------------------------------------
__global__ __launch_bounds__(256) void k_out(
    const float* __restrict__ emb, const void* __restrict__ uid,
    void* __restrict__ outv, const u32* __restrict__ flags)
{
  const int isBF = (int)flags[0];
  const int is64 = (int)flags[1];
  const int idx = blockIdx.x * 256 + threadIdx.x;
  const int w = idx & 1023;
  const int s = (idx >> 10) & 511;
  const int b = idx >> 19;
  const int id = ldI(uid, b * 512 + s, is64);
  const float wt = (id > 0) ? 1.f : ((id < 0) ? 2.f : 0.f);
  int au = (id < 0) ? (-id - 1) : (id - 1);
  au = max(0, min(31, au));
  const float v = emb[(size_t)(b * 32 + au) * 1024 + w] * wt;
  if (isBF) ((u16*)outv)[idx] = f2bf(v);
  else      ((float*)outv)[idx] = v;
}

// ---------------------------------------------------------------------------
// ws layout (serial dirs; G reused):
//  fp32-G (ws >= 143e6 B; R5 proved >=176.7MB): G 128Mi | Hhi 64Ki | Hlo 64Ki
//    | mp 4Mi | emb 4Mi | twT 400Ki | biasT | ctr | flags   ~= 136.8 MiB
//  fp16-G fallback: G 64Mi + same tail ~= 72.8 MiB
// ---------------------------------------------------------------------------
extern "C" void kernel_launch(void* const* d_in, const int* in_sizes, int n_in,
                              void* d_out, int out_size, void* d_ws, size_t ws_size,
                              hipStream_t stream) {
  (void)in_sizes; (void)n_in; (void)out_size;
  const void* X    = d_in[0];
  const void* uid  = d_in[1];
  const void* Wihf = d_in[2];
  const void* Whhf = d_in[3];
  const void* bihf = d_in[4];
  const void* bhhf = d_in[5];
  const void* Wihb = d_in[6];
  const void* Whhb = d_in[7];
  const void* bihb = d_in[8];
  const void* bhhb = d_in[9];
  const void* tw   = d_in[10];
  const void* tb   = d_in[11];
  const void* tt   = d_in[12];
  char* ws = (char*)d_ws;

  const int gHalf = (ws_size >= 143000000ull) ? 0 : 1;
  const size_t gBytes = gHalf ? 67108864ull : 134217728ull;
  const size_t oHhi = gBytes;
  const size_t oHlo = oHhi + 65536ull;
  const size_t omp  = oHlo + 65536ull;
  const size_t oem  = omp + 4194304ull;
  const size_t otw  = oem + 4194304ull;
  const size_t obi  = otw + 409600ull;
  const size_t oct  = obi + 512ull;
  const size_t oFL  = oct + 512ull;

  void*  G     = (void*)(ws + 0);
  u16*   Hhi   = (u16*)(ws + oHhi);
  u16*   Hlo   = (u16*)(ws + oHlo);
  float* mp    = (float*)(ws + omp);
  float* emb   = (float*)(ws + oem);
  float* twT   = (float*)(ws + otw);
  float* biasT = (float*)(ws + obi);
  unsigned* ctr = (unsigned*)(ws + oct);
  u32*   flags = (u32*)(ws + oFL);

  hipMemsetAsync(mp, 0, 4194304ull, stream);    // segment-max floor = 0
  hipMemsetAsync(ctr, 0, 512ull, stream);       // barrier counters
  k_probe<<<1, 256, 0, stream>>>((const u32*)X, (const u32*)uid, flags);

  // dir 0 (forward)
  k_xproj<<<dim3(256, 32), 256, 0, stream>>>(X, Wihf, bihf, bhhf, G, flags, gHalf);
  k_lstm<<<64, 256, 0, stream>>>(G, Whhf, Hhi, Hlo, mp, uid, ctr, 0, flags, gHalf);
  // dir 1 (backward) — G reused (stream-ordered)
  k_xproj<<<dim3(256, 32), 256, 0, stream>>>(X, Wihb, bihb, bhhb, G, flags, gHalf);
  k_lstm<<<64, 256, 0, stream>>>(G, Whhb, Hhi, Hlo, mp, uid, ctr + 32, 1, flags, gHalf);

  k_prep<<<401, 256, 0, stream>>>(tw, tb, twT, biasT, flags);
  k_topic<<<1024, 256, 0, stream>>>(mp, twT, biasT, tt, emb, flags);
  k_out<<<65536, 256, 0, stream>>>(emb, uid, d_out, flags);
}

// Round 2
// 12518.269 us; speedup vs baseline: 1.6095x; 1.2840x over previous
//
#include <hip/hip_runtime.h>
#include <hip/hip_fp16.h>

// GetTopic: biLSTM (B=32,S=512,W=1024,HP=512) -> fused per-utterance segment
// max -> topic softmax (T=100) -> weighted gather. Inputs fp32 (probe kept).
//
// R8 vs R7 (16.1 ms; k_lstm 2x7.0 ms, 13.8 us/step, all pipes <1%):
//  - Barrier: per-WG flag slots (one writer per 64B line) replace the single
//    64-RMW counter (same-address atomic serialization at MALL was the top
//    predicted cost). Detection parallelized: 64 lanes poll 64 slots, __all.
//  - h exchange is sc1 (agent-coherent, L2-bypass) end-to-end: stores via
//    relaxed-agent atomic u16 stores, loads via inline-asm
//    global_load_dwordx4 sc1 into a register array (single vmcnt(0) +
//    sched_barrier before the MFMA chain). NO buffer_inv / buffer_wbl2 per
//    step anymore; L2 stays warm for uid/G.
//  - If ws >= 278 MB: both dirs' G kept fp32 and both recurrences run
//    concurrently in ONE 128-WG launch (k_lstm2, independent slot groups).
// MFMA split-bf16 core, LDS exchange, fused mp max-pool unchanged.

typedef unsigned short u16;
typedef unsigned int   u32;
typedef __attribute__((ext_vector_type(8))) short short8;
typedef __attribute__((ext_vector_type(4))) float float4v;

__device__ __forceinline__ float bf2f(u16 u) { return __uint_as_float(((u32)u) << 16); }
__device__ __forceinline__ u16 f2bf(float f) {
  u32 u = __float_as_uint(f);
  u32 r = u + 0x7FFFu + ((u >> 16) & 1u);   // RNE
  return (u16)(r >> 16);
}
__device__ __forceinline__ float sigm(float x) { return 1.f / (1.f + expf(-x)); }

__device__ __forceinline__ float ldF(const void* p, size_t i, int isBF) {
  return isBF ? bf2f(((const u16*)p)[i]) : ((const float*)p)[i];
}
__device__ __forceinline__ int ldI(const void* p, int i, int is64) {
  return is64 ? (int)((const u32*)p)[(size_t)2 * i] : ((const int*)p)[i];
}

union U4S8 { uint4 u; short8 s; u16 us[8]; };

// ---------------------------------------------------------------------------
// Probe: input storage formats from raw bits (R4/R5-proven).
// flags[0]: 1 = float tensors bf16, 0 = fp32.  flags[1]: 1 = ids int64.
// ---------------------------------------------------------------------------
__global__ __launch_bounds__(256) void k_probe(
    const u32* __restrict__ X, const u32* __restrict__ U, u32* __restrict__ flags)
{
  __shared__ int cnt[2];
  if (threadIdx.x == 0) { cnt[0] = 0; cnt[1] = 0; }
  __syncthreads();
  int c0 = 0;
  for (int i = threadIdx.x; i < 1024; i += 256) {
    const u32 e = (X[i] >> 7) & 0xFFu;
    if (e >= 112u && e <= 143u) c0++;
  }
  int c1 = 0;
  {
    const u32 w = U[2 * threadIdx.x + 1];
    if (w == 0u || w == 0xFFFFFFFFu) c1++;
  }
  atomicAdd(&cnt[0], c0);
  atomicAdd(&cnt[1], c1);
  __syncthreads();
  if (threadIdx.x == 0) {
    flags[0] = (cnt[0] >= 512) ? 1u : 0u;
    flags[1] = (cnt[1] >= 128) ? 1u : 0u;
  }
}

// ---------------------------------------------------------------------------
// Phase 1 (per dir): G[s][n][b] = x @ Wih^T + (bih+bhh), fp32 (fp16 if gHalf).
// GEMM M=16384 (m=s*32+b), N=2048, K=1024. 64x64 tiles, 4x4/thread. (R5)
// ---------------------------------------------------------------------------
__global__ __launch_bounds__(256) void k_xproj(
    const void* __restrict__ X, const void* __restrict__ Wih,
    const void* __restrict__ bih, const void* __restrict__ bhh,
    void* __restrict__ Gv, const u32* __restrict__ flags, int gHalf)
{
  const int isBF = (int)flags[0];
  const int m0 = blockIdx.x * 64;
  const int n0 = blockIdx.y * 64;
  __shared__ float Asl[32][68];
  __shared__ float Bsl[32][68];
  const int tid = threadIdx.x;
  const int tx = tid & 15, ty = tid >> 4;
  const int lrow = tid >> 2;
  const int lkg  = (tid & 3) * 8;
  const int am = m0 + lrow;
  const int ab = am & 31, as_ = am >> 5;           // m = s*32 + b
  const size_t arow = ((size_t)ab * 512 + as_) * 1024;
  const size_t brow = (size_t)(n0 + lrow) * 1024;
  float acc[4][4] = {{0.f, 0.f, 0.f, 0.f}};
  for (int k0 = 0; k0 < 1024; k0 += 32) {
    float a8[8], b8[8];
    if (isBF) {
      const u16* Xh = (const u16*)X;
      const u16* Wh = (const u16*)Wih;
      uint4 va = *(const uint4*)(Xh + arow + k0 + lkg);
      uint4 vb = *(const uint4*)(Wh + brow + k0 + lkg);
      const u32 wa[4] = {va.x, va.y, va.z, va.w};
      const u32 wb[4] = {vb.x, vb.y, vb.z, vb.w};
#pragma unroll
      for (int q = 0; q < 4; ++q) {
        a8[2 * q]     = __uint_as_float(wa[q] << 16);
        a8[2 * q + 1] = __uint_as_float(wa[q] & 0xFFFF0000u);
        b8[2 * q]     = __uint_as_float(wb[q] << 16);
        b8[2 * q + 1] = __uint_as_float(wb[q] & 0xFFFF0000u);
      }
    } else {
      const float* Xf = (const float*)X;
      const float* Wf = (const float*)Wih;
      const float4 xa0 = *(const float4*)(Xf + arow + k0 + lkg);
      const float4 xa1 = *(const float4*)(Xf + arow + k0 + lkg + 4);
      const float4 xb0 = *(const float4*)(Wf + brow + k0 + lkg);
      const float4 xb1 = *(const float4*)(Wf + brow + k0 + lkg + 4);
      a8[0] = xa0.x; a8[1] = xa0.y; a8[2] = xa0.z; a8[3] = xa0.w;
      a8[4] = xa1.x; a8[5] = xa1.y; a8[6] = xa1.z; a8[7] = xa1.w;
      b8[0] = xb0.x; b8[1] = xb0.y; b8[2] = xb0.z; b8[3] = xb0.w;
      b8[4] = xb1.x; b8[5] = xb1.y; b8[6] = xb1.z; b8[7] = xb1.w;
    }
#pragma unroll
    for (int q = 0; q < 8; ++q) {
      Asl[lkg + q][lrow] = a8[q];
      Bsl[lkg + q][lrow] = b8[q];
    }
    __syncthreads();
#pragma unroll
    for (int k = 0; k < 32; ++k) {
      const float4 av = *(const float4*)&Asl[k][ty * 4];
      const float4 bv = *(const float4*)&Bsl[k][tx * 4];
      float a4[4] = {av.x, av.y, av.z, av.w};
      float b4[4] = {bv.x, bv.y, bv.z, bv.w};
#pragma unroll
      for (int i = 0; i < 4; ++i)
#pragma unroll
        for (int j = 0; j < 4; ++j)
          acc[i][j] = fmaf(a4[i], b4[j], acc[i][j]);
    }
    __syncthreads();
  }
  float bias[4];
#pragma unroll
  for (int j = 0; j < 4; ++j) {
    int n = n0 + tx * 4 + j;
    bias[j] = ldF(bih, n, isBF) + ldF(bhh, n, isBF);
  }
  const int mb = m0 + ty * 4;
  const int b0 = mb & 31, ss = mb >> 5;
#pragma unroll
  for (int j = 0; j < 4; ++j) {
    const int n = n0 + tx * 4 + j;
    const size_t off = ((size_t)ss * 2048 + n) * 32 + b0;
    if (gHalf) {
      ushort4 pk;
      pk.x = __half_as_ushort(__float2half(acc[0][j] + bias[j]));
      pk.y = __half_as_ushort(__float2half(acc[1][j] + bias[j]));
      pk.z = __half_as_ushort(__float2half(acc[2][j] + bias[j]));
      pk.w = __half_as_ushort(__float2half(acc[3][j] + bias[j]));
      *(uint2*)((u16*)Gv + off) = *(uint2*)&pk;
    } else {
      float4 pk;
      pk.x = acc[0][j] + bias[j]; pk.y = acc[1][j] + bias[j];
      pk.z = acc[2][j] + bias[j]; pk.w = acc[3][j] + bias[j];
      *(float4*)((float*)Gv + off) = pk;
    }
  }
}

// ---------------------------------------------------------------------------
// Phase 2: persistent recurrence body. 64 WGs per dir x 256 threads.
// WG owns 8 hidden units = 32 gate cols; Whh resident as split-bf16 MFMA
// fragments (3 chains hh/hl/lh ~ fp32). h exchanged via sc1 (MALL-coherent)
// 2x32KB ping-pong split-bf16 slabs -- no cache maintenance ops anywhere.
// Barrier: per-WG slot (64B line, single writer, relaxed sc1 store after
// syncthreads' vmcnt drain); consumers poll 64 slots with 64 lanes + __all.
// ---------------------------------------------------------------------------
__device__ __forceinline__ void lstm_body(
    const int wg, const int dir,
    const void* __restrict__ Gv, const void* __restrict__ Whh,
    u16* __restrict__ Hhi, u16* __restrict__ Hlo,
    float* __restrict__ mp, const void* __restrict__ uid,
    u32* __restrict__ slots, const u32* __restrict__ flags, const int gHalf)
{
  __shared__ float gl[1024];          // [col32][b32] gate preacts
  const int isBF = (int)flags[0];
  const int is64 = (int)flags[1];
  const int tid = threadIdx.x;
  const int j0 = wg * 8;
  const int lane = tid & 63;
  const int wid = tid >> 6;
  const int mt = wid & 1, nt = wid >> 1;
  const int l15 = lane & 15;
  const int quad = lane >> 4;
  const int nl = nt * 16 + l15;        // col 0..31 within WG
  const int n = ((nl >> 3) * 512) + j0 + (nl & 7);   // global gate row/col

  // B-frags: split-bf16 of Whh row n. B[n=l15][k=quad*8+j].
  short8 bhi[16], blo[16];
#pragma unroll 1
  for (int kt = 0; kt < 16; ++kt) {
    const int k0 = kt * 32 + quad * 8;
    float w[8];
    if (isBF) {
      const u16* Wh = (const u16*)Whh;
#pragma unroll
      for (int jj = 0; jj < 8; ++jj) w[jj] = bf2f(Wh[(size_t)n * 512 + k0 + jj]);
    } else {
      const float* Wf = (const float*)Whh;
      const float4 w0 = *(const float4*)(Wf + (size_t)n * 512 + k0);
      const float4 w1 = *(const float4*)(Wf + (size_t)n * 512 + k0 + 4);
      w[0] = w0.x; w[1] = w0.y; w[2] = w0.z; w[3] = w0.w;
      w[4] = w1.x; w[5] = w1.y; w[6] = w1.z; w[7] = w1.w;
    }
    U4S8 ph, pl;
#pragma unroll
    for (int jj = 0; jj < 8; ++jj) {
      const u16 hi = f2bf(w[jj]);
      const float rem = w[jj] - bf2f(hi);   // exact (Sterbenz)
      ph.us[jj] = hi; pl.us[jj] = f2bf(rem);
    }
    bhi[kt] = ph.s; blo[kt] = pl.s;
  }

  const int b_a = mt * 16 + l15;        // A row = batch
  const int cb = tid & 31;              // consumer: batch
  const int ciu = tid >> 5;             // consumer: unit 0..7
  float c = 0.f;

  // Per-thread G column offset; per-step offset = sidx*65536 + gcol.
  const size_t gcol = (size_t)n * 32 + (size_t)(mt * 16 + quad * 4);

  // Prefetch G for t=0 (plain cached loads -- L2 stays warm, no invalidates).
  float4v gpre;
  {
    const int s0 = dir ? 511 : 0;
    const size_t goff = (size_t)s0 * 65536 + gcol;
    if (gHalf) {
      const __half* Gp = (const __half*)Gv;
      gpre.x = __half2float(Gp[goff + 0]);
      gpre.y = __half2float(Gp[goff + 1]);
      gpre.z = __half2float(Gp[goff + 2]);
      gpre.w = __half2float(Gp[goff + 3]);
    } else {
      const float4 gv = *(const float4*)((const float*)Gv + goff);
      gpre.x = gv.x; gpre.y = gv.y; gpre.z = gv.z; gpre.w = gv.w;
    }
  }

  for (int t = 0; t < 512; ++t) {
    const int sidx = dir ? (511 - t) : t;
    if (t > 0) {
      // Parallel detection: lane i of wave 0 polls slot i (relaxed sc1 load;
      // no cache ops). All slots are single-writer -> no RMW serialization.
      if (tid < 64) {
        const u32 target = (u32)t;
        const u32* sl = slots + (size_t)tid * 16;
        for (;;) {
          const u32 v = __hip_atomic_load(sl, __ATOMIC_RELAXED, __HIP_MEMORY_SCOPE_AGENT);
          if (__all((int)(v >= target))) break;
          __builtin_amdgcn_s_sleep(1);
        }
      }
      __syncthreads();
    }

    // C-init from prefetched G (4 consecutive batches per lane, col n).
    float4v acc_hh = gpre;
    float4v acc_hl, acc_lh;
    acc_hl.x = 0.f; acc_hl.y = 0.f; acc_hl.z = 0.f; acc_hl.w = 0.f;
    acc_lh.x = 0.f; acc_lh.y = 0.f; acc_lh.z = 0.f; acc_lh.w = 0.f;

    if (t > 0) {
      const size_t abase = (size_t)((t - 1) & 1) * 16384 + (size_t)b_a * 512 + quad * 8;
      const u16* ah = Hhi + abase;
      const u16* al = Hlo + abase;
      // Issue all 32 sc1 (MALL-coherent) 16B loads, then one wait: a single
      // MALL latency for the whole fragment set.
      U4S8 va[16], vl[16];
#pragma unroll
      for (int kt = 0; kt < 16; ++kt) {
        asm volatile(
            "global_load_dwordx4 %0, %2, off offset:%4 sc1\n\t"
            "global_load_dwordx4 %1, %3, off offset:%4 sc1"
            : "=v"(va[kt].u), "=v"(vl[kt].u)
            : "v"(ah), "v"(al), "i"(kt * 64)
            : "memory");
      }
      asm volatile("s_waitcnt vmcnt(0)" ::: "memory");
      __builtin_amdgcn_sched_barrier(0);
#pragma unroll
      for (int kt = 0; kt < 16; ++kt) {
        acc_hh = __builtin_amdgcn_mfma_f32_16x16x32_bf16(va[kt].s, bhi[kt], acc_hh, 0, 0, 0);
        acc_hl = __builtin_amdgcn_mfma_f32_16x16x32_bf16(va[kt].s, blo[kt], acc_hl, 0, 0, 0);
        acc_lh = __builtin_amdgcn_mfma_f32_16x16x32_bf16(vl[kt].s, bhi[kt], acc_lh, 0, 0, 0);
      }
    }

    // Prefetch next step's G (independent; hides under exchange + barrier).
    if (t < 511) {
      const int sn = dir ? (510 - t) : (t + 1);
      const size_t goff = (size_t)sn * 65536 + gcol;
      if (gHalf) {
        const __half* Gp = (const __half*)Gv;
        gpre.x = __half2float(Gp[goff + 0]);
        gpre.y = __half2float(Gp[goff + 1]);
        gpre.z = __half2float(Gp[goff + 2]);
        gpre.w = __half2float(Gp[goff + 3]);
      } else {
        const float4 gv = *(const float4*)((const float*)Gv + goff);
        gpre.x = gv.x; gpre.y = gv.y; gpre.z = gv.z; gpre.w = gv.w;
      }
    }

    // exchange: D row (quad*4+r) = batch - mt*16, col l15 -> nl
    {
      const int base = nl * 32 + mt * 16 + quad * 4;
      gl[base + 0] = acc_hh.x + acc_hl.x + acc_lh.x;
      gl[base + 1] = acc_hh.y + acc_hl.y + acc_lh.y;
      gl[base + 2] = acc_hh.z + acc_hl.z + acc_lh.z;
      gl[base + 3] = acc_hh.w + acc_hl.w + acc_lh.w;
    }
    __syncthreads();

    float hval;
    int id;
    {
      const float a0 = gl[(0 * 8 + ciu) * 32 + cb];
      const float a1 = gl[(1 * 8 + ciu) * 32 + cb];
      const float a2 = gl[(2 * 8 + ciu) * 32 + cb];
      const float a3 = gl[(3 * 8 + ciu) * 32 + cb];
      const float ig = sigm(a0), fg = sigm(a1);
      const float gg = tanhf(a2), og = sigm(a3);
      c = fg * c + ig * gg;
      hval = og * tanhf(c);
      const u16 hh = f2bf(hval);
      const float rem = hval - bf2f(hh);
      const size_t so = (size_t)(t & 1) * 16384 + (size_t)cb * 512 + (j0 + ciu);
      // sc1 write-through stores: land at MALL, retired by the pre-barrier
      // vmcnt(0) -> visible agent-wide with no wbl2.
      __hip_atomic_store(Hhi + so, hh, __ATOMIC_RELAXED, __HIP_MEMORY_SCOPE_AGENT);
      __hip_atomic_store(Hlo + so, f2bf(rem), __ATOMIC_RELAXED, __HIP_MEMORY_SCOPE_AGENT);
      id = ldI(uid, cb * 512 + sidx, is64);
    }
    // __syncthreads drains every wave's vmcnt -> all sc1 h-stores are at the
    // MALL; the single relaxed slot store then publishes the step.
    __syncthreads();
    if (tid == 0)
      __hip_atomic_store(slots + (size_t)wg * 16, (u32)(t + 1),
                         __ATOMIC_RELAXED, __HIP_MEMORY_SCOPE_AGENT);
    // Deferred fused max-pool: overlaps the next poll. Visible to k_topic via
    // end-of-kernel release.
    if (id > 0 && hval > 0.f)
      atomicMax((int*)&mp[(size_t)(cb * 32 + (id - 1)) * 1024 + dir * 512 + (j0 + ciu)],
                __float_as_int(hval));
  }
}

__global__ __launch_bounds__(256) void k_lstm(
    const void* __restrict__ Gv, const void* __restrict__ Whh,
    u16* __restrict__ Hhi, u16* __restrict__ Hlo,
    float* __restrict__ mp, const void* __restrict__ uid,
    u32* __restrict__ slots, int dir,
    const u32* __restrict__ flags, int gHalf)
{
  lstm_body((int)blockIdx.x, dir, Gv, Whh, Hhi, Hlo, mp, uid, slots, flags, gHalf);
}

// Fused dual-direction variant: WGs 0..63 = dir0, 64..127 = dir1. Each dir
// has its own G, h slabs, and slot group; mp is shared (atomicMax, disjoint
// halves). Requires ws >= 278 MB (both G fp32).
__global__ __launch_bounds__(256) void k_lstm2(
    const void* __restrict__ G0, const void* __restrict__ G1,
    const void* __restrict__ Whhf, const void* __restrict__ Whhb,
    u16* __restrict__ Hh0, u16* __restrict__ Hl0,
    u16* __restrict__ Hh1, u16* __restrict__ Hl1,
    float* __restrict__ mp, const void* __restrict__ uid,
    u32* __restrict__ slots, const u32* __restrict__ flags)
{
  const int d = ((int)blockIdx.x >= 64) ? 1 : 0;
  const int wg = (int)blockIdx.x & 63;
  lstm_body(wg, d, d ? G1 : G0, d ? Whhb : Whhf,
            d ? Hh1 : Hh0, d ? Hl1 : Hl0, mp, uid,
            slots + (size_t)d * 1024, flags, 0);
}

// ---------------------------------------------------------------------------
// Phase 4a: topic_weights -> twT[k][t] fp32, bias -> fp32.
// ---------------------------------------------------------------------------
__global__ __launch_bounds__(256) void k_prep(
    const void* __restrict__ tw, const void* __restrict__ tb,
    float* __restrict__ twT, float* __restrict__ biasT, const u32* __restrict__ flags)
{
  const int isBF = (int)flags[0];
  const int idx = blockIdx.x * 256 + threadIdx.x;
  if (idx < 102400) {
    const int t = idx >> 10, k = idx & 1023;
    twT[k * 100 + t] = ldF(tw, idx, isBF);
  } else if (idx < 102500) {
    biasT[idx - 102400] = ldF(tb, idx - 102400, isBF);
  }
}

// ---------------------------------------------------------------------------
// Phase 4: per (b,u): logits(100) -> softmax -> emb row (fp32).
// ---------------------------------------------------------------------------
__global__ __launch_bounds__(256) void k_topic(
    const float* __restrict__ mp, const float* __restrict__ twT,
    const float* __restrict__ biasT, const void* __restrict__ table,
    float* __restrict__ emb, const u32* __restrict__ flags)
{
  const int isBF = (int)flags[0];
  const int bu = blockIdx.x;
  const int tid = threadIdx.x;
  __shared__ float lrow[1024];
  __shared__ float red[128];
  __shared__ float parr[128];
  for (int i = tid; i < 1024; i += 256) lrow[i] = mp[(size_t)bu * 1024 + i];
  __syncthreads();
  float lacc = -1e30f;
  if (tid < 100) {
    lacc = biasT[tid];
    for (int k = 0; k < 1024; ++k) lacc = fmaf(lrow[k], twT[k * 100 + tid], lacc);
  }
  if (tid < 128) red[tid] = (tid < 100) ? lacc : -1e30f;
  __syncthreads();
  for (int off = 64; off > 0; off >>= 1) {
    if (tid < off) red[tid] = fmaxf(red[tid], red[tid + off]);
    __syncthreads();
  }
  const float mxv = red[0];
  __syncthreads();
  const float e = (tid < 100) ? expf(lacc - mxv) : 0.f;
  if (tid < 128) red[tid] = e;
  __syncthreads();
  for (int off = 64; off > 0; off >>= 1) {
    if (tid < off) red[tid] += red[tid + off];
    __syncthreads();
  }
  const float inv = 1.f / red[0];
  if (tid < 128) parr[tid] = e * inv;
  __syncthreads();
#pragma unroll
  for (int r = 0; r < 4; ++r) {
    const int w = tid + 256 * r;
    float a = 0.f;
    for (int t = 0; t < 100; ++t)
      a = fmaf(parr[t], ldF(table, (size_t)t * 1024 + w, isBF), a);
    emb[(size_t)bu * 1024 + w] = a;
  }
}

// ---------------------------------------------------------------------------
// Phase 5: out = emb[b][clip(|uid|-1,0,31)][w] * {1,2,0}. Dtype by flag.
// ---------------------------------------------------------------------------
__global__ __launch_bounds__(256) void k_out(
    const float* __restrict__ emb, const void* __restrict__ uid,
    void* __restrict__ outv, const u32* __restrict__ flags)
{
  const int isBF = (int)flags[0];
  const int is64 = (int)flags[1];
  const int idx = blockIdx.x * 256 + threadIdx.x;
  const int w = idx & 1023;
  const int s = (idx >> 10) & 511;
  const int b = idx >> 19;
  const int id = ldI(uid, b * 512 + s, is64);
  const float wt = (id > 0) ? 1.f : ((id < 0) ? 2.f : 0.f);
  int au = (id < 0) ? (-id - 1) : (id - 1);
  au = max(0, min(31, au));
  const float v = emb[(size_t)(b * 32 + au) * 1024 + w] * wt;
  if (isBF) ((u16*)outv)[idx] = f2bf(v);
  else      ((float*)outv)[idx] = v;
}

// ---------------------------------------------------------------------------
// ws layouts:
//  FUSED (ws >= 277,505,024 B): G0 128Mi | G1 128Mi | Hh0,Hl0,Hh1,Hl1 4x64Ki
//    | mp 4Mi | emb 4Mi | twT 400Ki | biasT 512 | slots 8Ki | flags 512
//  SERIAL fp32-G (ws >= 143e6; R5 proved >=176.7MB): G 128Mi | Hhi,Hlo 2x64Ki
//    | mp | emb | twT | biasT | slots 8Ki | flags
//  SERIAL fp16-G fallback: G 64Mi + same tail.
// ---------------------------------------------------------------------------
extern "C" void kernel_launch(void* const* d_in, const int* in_sizes, int n_in,
                              void* d_out, int out_size, void* d_ws, size_t ws_size,
                              hipStream_t stream) {
  (void)in_sizes; (void)n_in; (void)out_size;
  const void* X    = d_in[0];
  const void* uid  = d_in[1];
  const void* Wihf = d_in[2];
  const void* Whhf = d_in[3];
  const void* bihf = d_in[4];
  const void* bhhf = d_in[5];
  const void* Wihb = d_in[6];
  const void* Whhb = d_in[7];
  const void* bihb = d_in[8];
  const void* bhhb = d_in[9];
  const void* tw   = d_in[10];
  const void* tb   = d_in[11];
  const void* tt   = d_in[12];
  char* ws = (char*)d_ws;

  const int fused = (ws_size >= 277505024ull) ? 1 : 0;

  if (fused) {
    void*  G0  = (void*)(ws + 0);
    void*  G1  = (void*)(ws + 134217728ull);
    const size_t oH = 268435456ull;
    u16*   Hh0 = (u16*)(ws + oH);
    u16*   Hl0 = (u16*)(ws + oH + 65536ull);
    u16*   Hh1 = (u16*)(ws + oH + 131072ull);
    u16*   Hl1 = (u16*)(ws + oH + 196608ull);
    const size_t omp = oH + 262144ull;
    float* mp    = (float*)(ws + omp);
    const size_t oem = omp + 4194304ull;
    float* emb   = (float*)(ws + oem);
    const size_t otw = oem + 4194304ull;
    float* twT   = (float*)(ws + otw);
    const size_t obi = otw + 409600ull;
    float* biasT = (float*)(ws + obi);
    const size_t osl = obi + 512ull;
    u32*   slots = (u32*)(ws + osl);
    const size_t oFL = osl + 8192ull;
    u32*   flags = (u32*)(ws + oFL);

    hipMemsetAsync(mp, 0, 4194304ull, stream);
    hipMemsetAsync(slots, 0, 8192ull, stream);
    k_probe<<<1, 256, 0, stream>>>((const u32*)X, (const u32*)uid, flags);

    k_xproj<<<dim3(256, 32), 256, 0, stream>>>(X, Wihf, bihf, bhhf, G0, flags, 0);
    k_xproj<<<dim3(256, 32), 256, 0, stream>>>(X, Wihb, bihb, bhhb, G1, flags, 0);
    k_lstm2<<<128, 256, 0, stream>>>(G0, G1, Whhf, Whhb, Hh0, Hl0, Hh1, Hl1,
                                     mp, uid, slots, flags);

    k_prep<<<401, 256, 0, stream>>>(tw, tb, twT, biasT, flags);
    k_topic<<<1024, 256, 0, stream>>>(mp, twT, biasT, tt, emb, flags);
    k_out<<<65536, 256, 0, stream>>>(emb, uid, d_out, flags);
    return;
  }

  const int gHalf = (ws_size >= 143000000ull) ? 0 : 1;
  const size_t gBytes = gHalf ? 67108864ull : 134217728ull;
  const size_t oHhi = gBytes;
  const size_t oHlo = oHhi + 65536ull;
  const size_t omp  = oHlo + 65536ull;
  const size_t oem  = omp + 4194304ull;
  const size_t otw  = oem + 4194304ull;
  const size_t obi  = otw + 409600ull;
  const size_t osl  = obi + 512ull;
  const size_t oFL  = osl + 8192ull;

  void*  G     = (void*)(ws + 0);
  u16*   Hhi   = (u16*)(ws + oHhi);
  u16*   Hlo   = (u16*)(ws + oHlo);
  float* mp    = (float*)(ws + omp);
  float* emb   = (float*)(ws + oem);
  float* twT   = (float*)(ws + otw);
  float* biasT = (float*)(ws + obi);
  u32*   slots = (u32*)(ws + osl);
  u32*   flags = (u32*)(ws + oFL);

  hipMemsetAsync(mp, 0, 4194304ull, stream);    // segment-max floor = 0
  hipMemsetAsync(slots, 0, 8192ull, stream);    // barrier slots (both dirs)
  k_probe<<<1, 256, 0, stream>>>((const u32*)X, (const u32*)uid, flags);

  // dir 0 (forward)
  k_xproj<<<dim3(256, 32), 256, 0, stream>>>(X, Wihf, bihf, bhhf, G, flags, gHalf);
  k_lstm<<<64, 256, 0, stream>>>(G, Whhf, Hhi, Hlo, mp, uid, slots, 0, flags, gHalf);
  // dir 1 (backward) — G reused (stream-ordered)
  k_xproj<<<dim3(256, 32), 256, 0, stream>>>(X, Wihb, bihb, bhhb, G, flags, gHalf);
  k_lstm<<<64, 256, 0, stream>>>(G, Whhb, Hhi, Hlo, mp, uid, slots + 1024, 1, flags, gHalf);

  k_prep<<<401, 256, 0, stream>>>(tw, tb, twT, biasT, flags);
  k_topic<<<1024, 256, 0, stream>>>(mp, twT, biasT, tt, emb, flags);
  k_out<<<65536, 256, 0, stream>>>(emb, uid, d_out, flags);
}

// Round 5
// 12088.741 us; speedup vs baseline: 1.6667x; 1.0355x over previous
//
#include <hip/hip_runtime.h>
#include <hip/hip_fp16.h>

// GetTopic: biLSTM (B=32,S=512,W=1024,HP=512) -> fused per-utterance segment
// max -> topic softmax (T=100) -> weighted gather. Inputs fp32 (probe kept).
//
// R11 = R8 (12.5 ms, PROVEN: 64 WGs x 256 thr, 10.1 us/step) + two isolated,
// counter-motivated deltas. R9/R10's 512-thread restructure is dropped (R10
// aborted at runtime; 8-wave WG + inline-asm register arrays sit on the
// 256-VGPR occupancy cliff).
//  - Delta 1 (WRITE_SIZE 319 MB -> 2B sc1 store amplification): h stores are
//    LDS-staged; wave 0 re-gathers and issues 128x 8B relaxed-agent stores
//    (coalesced 16B runs), one vmcnt(0), tid0 publishes. Other waves do no
//    global h stores at all.
//  - Delta 2 (poll congestion): barrier slots spread 4 KB apart (one MALL
//    slice each). Dir1 reuses slots via monotone target base +512.
// MFMA split-bf16 core, sc1 h-exchange loads, fused mp max-pool unchanged.

typedef unsigned short u16;
typedef unsigned int   u32;
typedef unsigned long long u64;
typedef __attribute__((ext_vector_type(8))) short short8;
typedef __attribute__((ext_vector_type(4))) float float4v;

__device__ __forceinline__ float bf2f(u16 u) { return __uint_as_float(((u32)u) << 16); }
__device__ __forceinline__ u16 f2bf(float f) {
  u32 u = __float_as_uint(f);
  u32 r = u + 0x7FFFu + ((u >> 16) & 1u);   // RNE
  return (u16)(r >> 16);
}
__device__ __forceinline__ float sigm(float x) { return 1.f / (1.f + expf(-x)); }

__device__ __forceinline__ float ldF(const void* p, size_t i, int isBF) {
  return isBF ? bf2f(((const u16*)p)[i]) : ((const float*)p)[i];
}
__device__ __forceinline__ int ldI(const void* p, int i, int is64) {
  return is64 ? (int)((const u32*)p)[(size_t)2 * i] : ((const int*)p)[i];
}

union U4S8 { uint4 u; short8 s; u16 us[8]; };

// ---------------------------------------------------------------------------
// Probe: input storage formats from raw bits (R4/R5-proven).
// flags[0]: 1 = float tensors bf16, 0 = fp32.  flags[1]: 1 = ids int64.
// ---------------------------------------------------------------------------
__global__ __launch_bounds__(256) void k_probe(
    const u32* __restrict__ X, const u32* __restrict__ U, u32* __restrict__ flags)
{
  __shared__ int cnt[2];
  if (threadIdx.x == 0) { cnt[0] = 0; cnt[1] = 0; }
  __syncthreads();
  int c0 = 0;
  for (int i = threadIdx.x; i < 1024; i += 256) {
    const u32 e = (X[i] >> 7) & 0xFFu;
    if (e >= 112u && e <= 143u) c0++;
  }
  int c1 = 0;
  {
    const u32 w = U[2 * threadIdx.x + 1];
    if (w == 0u || w == 0xFFFFFFFFu) c1++;
  }
  atomicAdd(&cnt[0], c0);
  atomicAdd(&cnt[1], c1);
  __syncthreads();
  if (threadIdx.x == 0) {
    flags[0] = (cnt[0] >= 512) ? 1u : 0u;
    flags[1] = (cnt[1] >= 128) ? 1u : 0u;
  }
}

// ---------------------------------------------------------------------------
// Phase 1 (per dir): G[s][n][b] = x @ Wih^T + (bih+bhh), fp32 (fp16 if gHalf).
// GEMM M=16384 (m=s*32+b), N=2048, K=1024. 64x64 tiles, 4x4/thread. (R5)
// ---------------------------------------------------------------------------
__global__ __launch_bounds__(256) void k_xproj(
    const void* __restrict__ X, const void* __restrict__ Wih,
    const void* __restrict__ bih, const void* __restrict__ bhh,
    void* __restrict__ Gv, const u32* __restrict__ flags, int gHalf)
{
  const int isBF = (int)flags[0];
  const int m0 = blockIdx.x * 64;
  const int n0 = blockIdx.y * 64;
  __shared__ float Asl[32][68];
  __shared__ float Bsl[32][68];
  const int tid = threadIdx.x;
  const int tx = tid & 15, ty = tid >> 4;
  const int lrow = tid >> 2;
  const int lkg  = (tid & 3) * 8;
  const int am = m0 + lrow;
  const int ab = am & 31, as_ = am >> 5;           // m = s*32 + b
  const size_t arow = ((size_t)ab * 512 + as_) * 1024;
  const size_t brow = (size_t)(n0 + lrow) * 1024;
  float acc[4][4] = {{0.f, 0.f, 0.f, 0.f}};
  for (int k0 = 0; k0 < 1024; k0 += 32) {
    float a8[8], b8[8];
    if (isBF) {
      const u16* Xh = (const u16*)X;
      const u16* Wh = (const u16*)Wih;
      uint4 va = *(const uint4*)(Xh + arow + k0 + lkg);
      uint4 vb = *(const uint4*)(Wh + brow + k0 + lkg);
      const u32 wa[4] = {va.x, va.y, va.z, va.w};
      const u32 wb[4] = {vb.x, vb.y, vb.z, vb.w};
#pragma unroll
      for (int q = 0; q < 4; ++q) {
        a8[2 * q]     = __uint_as_float(wa[q] << 16);
        a8[2 * q + 1] = __uint_as_float(wa[q] & 0xFFFF0000u);
        b8[2 * q]     = __uint_as_float(wb[q] << 16);
        b8[2 * q + 1] = __uint_as_float(wb[q] & 0xFFFF0000u);
      }
    } else {
      const float* Xf = (const float*)X;
      const float* Wf = (const float*)Wih;
      const float4 xa0 = *(const float4*)(Xf + arow + k0 + lkg);
      const float4 xa1 = *(const float4*)(Xf + arow + k0 + lkg + 4);
      const float4 xb0 = *(const float4*)(Wf + brow + k0 + lkg);
      const float4 xb1 = *(const float4*)(Wf + brow + k0 + lkg + 4);
      a8[0] = xa0.x; a8[1] = xa0.y; a8[2] = xa0.z; a8[3] = xa0.w;
      a8[4] = xa1.x; a8[5] = xa1.y; a8[6] = xa1.z; a8[7] = xa1.w;
      b8[0] = xb0.x; b8[1] = xb0.y; b8[2] = xb0.z; b8[3] = xb0.w;
      b8[4] = xb1.x; b8[5] = xb1.y; b8[6] = xb1.z; b8[7] = xb1.w;
    }
#pragma unroll
    for (int q = 0; q < 8; ++q) {
      Asl[lkg + q][lrow] = a8[q];
      Bsl[lkg + q][lrow] = b8[q];
    }
    __syncthreads();
#pragma unroll
    for (int k = 0; k < 32; ++k) {
      const float4 av = *(const float4*)&Asl[k][ty * 4];
      const float4 bv = *(const float4*)&Bsl[k][tx * 4];
      float a4[4] = {av.x, av.y, av.z, av.w};
      float b4[4] = {bv.x, bv.y, bv.z, bv.w};
#pragma unroll
      for (int i = 0; i < 4; ++i)
#pragma unroll
        for (int j = 0; j < 4; ++j)
          acc[i][j] = fmaf(a4[i], b4[j], acc[i][j]);
    }
    __syncthreads();
  }
  float bias[4];
#pragma unroll
  for (int j = 0; j < 4; ++j) {
    int n = n0 + tx * 4 + j;
    bias[j] = ldF(bih, n, isBF) + ldF(bhh, n, isBF);
  }
  const int mb = m0 + ty * 4;
  const int b0 = mb & 31, ss = mb >> 5;
#pragma unroll
  for (int j = 0; j < 4; ++j) {
    const int n = n0 + tx * 4 + j;
    const size_t off = ((size_t)ss * 2048 + n) * 32 + b0;
    if (gHalf) {
      ushort4 pk;
      pk.x = __half_as_ushort(__float2half(acc[0][j] + bias[j]));
      pk.y = __half_as_ushort(__float2half(acc[1][j] + bias[j]));
      pk.z = __half_as_ushort(__float2half(acc[2][j] + bias[j]));
      pk.w = __half_as_ushort(__float2half(acc[3][j] + bias[j]));
      *(uint2*)((u16*)Gv + off) = *(uint2*)&pk;
    } else {
      float4 pk;
      pk.x = acc[0][j] + bias[j]; pk.y = acc[1][j] + bias[j];
      pk.z = acc[2][j] + bias[j]; pk.w = acc[3][j] + bias[j];
      *(float4*)((float*)Gv + off) = pk;
    }
  }
}

// ---------------------------------------------------------------------------
// Phase 2: persistent recurrence, one launch per dir. 64 WGs x 256 threads
// (R8-proven config). WG owns 8 hidden units = 32 gate cols; Whh resident
// as split-bf16 MFMA fragments (3 chains hh/hl/lh ~ fp32). h exchanged via
// sc1 (MALL-coherent) 2x32KB ping-pong split-bf16 slabs.
// R11: h stores LDS-staged -> wave 0 issues 128x 8B agent stores (coalesced
// 16B runs), one vmcnt(0), tid0 publishes its 4KB-spread slot. Lanes of
// wave 0 poll 64 spread slots, __all join. Dir1 target base +512.
// ---------------------------------------------------------------------------
__global__ __launch_bounds__(256) void k_lstm(
    const void* __restrict__ Gv, const void* __restrict__ Whh,
    u16* __restrict__ Hhi, u16* __restrict__ Hlo,
    float* __restrict__ mp, const void* __restrict__ uid,
    u32* __restrict__ slots, int dir,
    const u32* __restrict__ flags, int gHalf)
{
  __shared__ float gl[1024];                    // [col32][b32] gate preacts
  __shared__ __align__(16) u16 shh[256];        // staged h hi: [b32][u8]
  __shared__ __align__(16) u16 shl[256];        // staged h lo: [b32][u8]
  const int isBF = (int)flags[0];
  const int is64 = (int)flags[1];
  const int tid = threadIdx.x;
  const int wg = (int)blockIdx.x;
  const int j0 = wg * 8;
  const int lane = tid & 63;
  const int wid = tid >> 6;
  const int mt = wid & 1, nt = wid >> 1;
  const int l15 = lane & 15;
  const int quad = lane >> 4;
  const int nl = nt * 16 + l15;        // col 0..31 within WG
  const int n = ((nl >> 3) * 512) + j0 + (nl & 7);   // global gate row/col

  // B-frags: split-bf16 of Whh row n. B[n=l15][k=quad*8+j].
  short8 bhi[16], blo[16];
#pragma unroll 1
  for (int kt = 0; kt < 16; ++kt) {
    const int k0 = kt * 32 + quad * 8;
    float w[8];
    if (isBF) {
      const u16* Wh = (const u16*)Whh;
#pragma unroll
      for (int jj = 0; jj < 8; ++jj) w[jj] = bf2f(Wh[(size_t)n * 512 + k0 + jj]);
    } else {
      const float* Wf = (const float*)Whh;
      const float4 w0 = *(const float4*)(Wf + (size_t)n * 512 + k0);
      const float4 w1 = *(const float4*)(Wf + (size_t)n * 512 + k0 + 4);
      w[0] = w0.x; w[1] = w0.y; w[2] = w0.z; w[3] = w0.w;
      w[4] = w1.x; w[5] = w1.y; w[6] = w1.z; w[7] = w1.w;
    }
    U4S8 ph, pl;
#pragma unroll
    for (int jj = 0; jj < 8; ++jj) {
      const u16 hi = f2bf(w[jj]);
      const float rem = w[jj] - bf2f(hi);   // exact (Sterbenz)
      ph.us[jj] = hi; pl.us[jj] = f2bf(rem);
    }
    bhi[kt] = ph.s; blo[kt] = pl.s;
  }

  const int b_a = mt * 16 + l15;        // A row = batch
  const int cb = tid & 31;              // consumer: batch
  const int ciu = tid >> 5;             // consumer: unit 0..7
  float c = 0.f;

  const u32 tbase = (u32)dir * 512u;    // slot target base (dir1 reuses slots)

  // Per-thread G column offset; per-step offset = sidx*65536 + gcol.
  const size_t gcol = (size_t)n * 32 + (size_t)(mt * 16 + quad * 4);

  // Prefetch G for t=0 (plain cached loads -- L2 stays warm).
  float4v gpre;
  {
    const int s0 = dir ? 511 : 0;
    const size_t goff = (size_t)s0 * 65536 + gcol;
    if (gHalf) {
      const __half* Gp = (const __half*)Gv;
      gpre.x = __half2float(Gp[goff + 0]);
      gpre.y = __half2float(Gp[goff + 1]);
      gpre.z = __half2float(Gp[goff + 2]);
      gpre.w = __half2float(Gp[goff + 3]);
    } else {
      const float4 gv = *(const float4*)((const float*)Gv + goff);
      gpre.x = gv.x; gpre.y = gv.y; gpre.z = gv.z; gpre.w = gv.w;
    }
  }

  for (int t = 0; t < 512; ++t) {
    const int sidx = dir ? (511 - t) : t;
    if (t > 0) {
      // Parallel detection: lane i of wave 0 polls slot i (4KB spread ->
      // distinct MALL slices). Single-writer slots, relaxed sc1 loads.
      if (tid < 64) {
        const u32 target = tbase + (u32)t;
        const u32* sl = slots + (size_t)lane * 1024;   // 4KB stride
        for (;;) {
          const u32 v = __hip_atomic_load(sl, __ATOMIC_RELAXED, __HIP_MEMORY_SCOPE_AGENT);
          if (__all((int)(v >= target))) break;
          __builtin_amdgcn_s_sleep(1);
        }
      }
      __syncthreads();
    }

    // C-init from prefetched G (4 consecutive batches per lane, col n).
    float4v acc_hh = gpre;
    float4v acc_hl, acc_lh;
    acc_hl.x = 0.f; acc_hl.y = 0.f; acc_hl.z = 0.f; acc_hl.w = 0.f;
    acc_lh.x = 0.f; acc_lh.y = 0.f; acc_lh.z = 0.f; acc_lh.w = 0.f;

    if (t > 0) {
      const size_t abase = (size_t)((t - 1) & 1) * 16384 + (size_t)b_a * 512 + quad * 8;
      const u16* ah = Hhi + abase;
      const u16* al = Hlo + abase;
      // Issue all 32 sc1 (MALL-coherent) 16B loads, then one wait.
      U4S8 va[16], vl[16];
#pragma unroll
      for (int kt = 0; kt < 16; ++kt) {
        asm volatile(
            "global_load_dwordx4 %0, %2, off offset:%4 sc1\n\t"
            "global_load_dwordx4 %1, %3, off offset:%4 sc1"
            : "=v"(va[kt].u), "=v"(vl[kt].u)
            : "v"(ah), "v"(al), "i"(kt * 64)
            : "memory");
      }
      asm volatile("s_waitcnt vmcnt(0)" ::: "memory");
      __builtin_amdgcn_sched_barrier(0);
#pragma unroll
      for (int kt = 0; kt < 16; ++kt) {
        acc_hh = __builtin_amdgcn_mfma_f32_16x16x32_bf16(va[kt].s, bhi[kt], acc_hh, 0, 0, 0);
        acc_hl = __builtin_amdgcn_mfma_f32_16x16x32_bf16(va[kt].s, blo[kt], acc_hl, 0, 0, 0);
        acc_lh = __builtin_amdgcn_mfma_f32_16x16x32_bf16(vl[kt].s, bhi[kt], acc_lh, 0, 0, 0);
      }
    }

    // Prefetch next step's G (independent; hides under exchange + barrier).
    if (t < 511) {
      const int sn = dir ? (510 - t) : (t + 1);
      const size_t goff = (size_t)sn * 65536 + gcol;
      if (gHalf) {
        const __half* Gp = (const __half*)Gv;
        gpre.x = __half2float(Gp[goff + 0]);
        gpre.y = __half2float(Gp[goff + 1]);
        gpre.z = __half2float(Gp[goff + 2]);
        gpre.w = __half2float(Gp[goff + 3]);
      } else {
        const float4 gv = *(const float4*)((const float*)Gv + goff);
        gpre.x = gv.x; gpre.y = gv.y; gpre.z = gv.z; gpre.w = gv.w;
      }
    }

    // exchange: D row (quad*4+r) = batch - mt*16, col l15 -> nl
    {
      const int base = nl * 32 + mt * 16 + quad * 4;
      gl[base + 0] = acc_hh.x + acc_hl.x + acc_lh.x;
      gl[base + 1] = acc_hh.y + acc_hl.y + acc_lh.y;
      gl[base + 2] = acc_hh.z + acc_hl.z + acc_lh.z;
      gl[base + 3] = acc_hh.w + acc_hl.w + acc_lh.w;
    }
    __syncthreads();

    float hval;
    int id;
    {
      const float a0 = gl[(0 * 8 + ciu) * 32 + cb];
      const float a1 = gl[(1 * 8 + ciu) * 32 + cb];
      const float a2 = gl[(2 * 8 + ciu) * 32 + cb];
      const float a3 = gl[(3 * 8 + ciu) * 32 + cb];
      const float ig = sigm(a0), fg = sigm(a1);
      const float gg = tanhf(a2), og = sigm(a3);
      c = fg * c + ig * gg;
      hval = og * tanhf(c);
      const u16 hh = f2bf(hval);
      shh[cb * 8 + ciu] = hh;
      shl[cb * 8 + ciu] = f2bf(hval - bf2f(hh));
      id = ldI(uid, cb * 512 + sidx, is64);
    }
    __syncthreads();

    // Wave 0: re-gather staged h, 128x 8B agent stores (16B runs per batch),
    // one drain, tid0 publishes. Other waves proceed to atomicMax.
    if (tid < 64) {
      const int sb = lane >> 1, q = lane & 1;       // batch, 4-unit chunk
      const u64 vh = ((const u64*)shh)[sb * 2 + q];
      const u64 vo = ((const u64*)shl)[sb * 2 + q];
      const size_t so = (size_t)(t & 1) * 16384 + (size_t)sb * 512 + j0 + q * 4;
      __hip_atomic_store((u64*)(Hhi + so), vh, __ATOMIC_RELAXED, __HIP_MEMORY_SCOPE_AGENT);
      __hip_atomic_store((u64*)(Hlo + so), vo, __ATOMIC_RELAXED, __HIP_MEMORY_SCOPE_AGENT);
      asm volatile("s_waitcnt vmcnt(0)" ::: "memory");
      if (tid == 0)
        __hip_atomic_store(slots + (size_t)wg * 1024, tbase + (u32)(t + 1),
                           __ATOMIC_RELAXED, __HIP_MEMORY_SCOPE_AGENT);
    }
    // Deferred fused max-pool: overlaps the next poll. Visible to k_topic via
    // end-of-kernel release.
    if (id > 0 && hval > 0.f)
      atomicMax((int*)&mp[(size_t)(cb * 32 + (id - 1)) * 1024 + dir * 512 + (j0 + ciu)],
                __float_as_int(hval));
  }
}

// ---------------------------------------------------------------------------
// Phase 4a: topic_weights -> twT[k][t] fp32, bias -> fp32.
// ---------------------------------------------------------------------------
__global__ __launch_bounds__(256) void k_prep(
    const void* __restrict__ tw, const void* __restrict__ tb,
    float* __restrict__ twT, float* __restrict__ biasT, const u32* __restrict__ flags)
{
  const int isBF = (int)flags[0];
  const int idx = blockIdx.x * 256 + threadIdx.x;
  if (idx < 102400) {
    const int t = idx >> 10, k = idx & 1023;
    twT[k * 100 + t] = ldF(tw, idx, isBF);
  } else if (idx < 102500) {
    biasT[idx - 102400] = ldF(tb, idx - 102400, isBF);
  }
}

// ---------------------------------------------------------------------------
// Phase 4: per (b,u): logits(100) -> softmax -> emb row (fp32).
// ---------------------------------------------------------------------------
__global__ __launch_bounds__(256) void k_topic(
    const float* __restrict__ mp, const float* __restrict__ twT,
    const float* __restrict__ biasT, const void* __restrict__ table,
    float* __restrict__ emb, const u32* __restrict__ flags)
{
  const int isBF = (int)flags[0];
  const int bu = blockIdx.x;
  const int tid = threadIdx.x;
  __shared__ float lrow[1024];
  __shared__ float red[128];
  __shared__ float parr[128];
  for (int i = tid; i < 1024; i += 256) lrow[i] = mp[(size_t)bu * 1024 + i];
  __syncthreads();
  float lacc = -1e30f;
  if (tid < 100) {
    lacc = biasT[tid];
    for (int k = 0; k < 1024; ++k) lacc = fmaf(lrow[k], twT[k * 100 + tid], lacc);
  }
  if (tid < 128) red[tid] = (tid < 100) ? lacc : -1e30f;
  __syncthreads();
  for (int off = 64; off > 0; off >>= 1) {
    if (tid < off) red[tid] = fmaxf(red[tid], red[tid + off]);
    __syncthreads();
  }
  const float mxv = red[0];
  __syncthreads();
  const float e = (tid < 100) ? expf(lacc - mxv) : 0.f;
  if (tid < 128) red[tid] = e;
  __syncthreads();
  for (int off = 64; off > 0; off >>= 1) {
    if (tid < off) red[tid] += red[tid + off];
    __syncthreads();
  }
  const float inv = 1.f / red[0];
  if (tid < 128) parr[tid] = e * inv;
  __syncthreads();
#pragma unroll
  for (int r = 0; r < 4; ++r) {
    const int w = tid + 256 * r;
    float a = 0.f;
    for (int t = 0; t < 100; ++t)
      a = fmaf(parr[t], ldF(table, (size_t)t * 1024 + w, isBF), a);
    emb[(size_t)bu * 1024 + w] = a;
  }
}

// ---------------------------------------------------------------------------
// Phase 5: out = emb[b][clip(|uid|-1,0,31)][w] * {1,2,0}. Dtype by flag.
// ---------------------------------------------------------------------------
__global__ __launch_bounds__(256) void k_out(
    const float* __restrict__ emb, const void* __restrict__ uid,
    void* __restrict__ outv, const u32* __restrict__ flags)
{
  const int isBF = (int)flags[0];
  const int is64 = (int)flags[1];
  const int idx = blockIdx.x * 256 + threadIdx.x;
  const int w = idx & 1023;
  const int s = (idx >> 10) & 511;
  const int b = idx >> 19;
  const int id = ldI(uid, b * 512 + s, is64);
  const float wt = (id > 0) ? 1.f : ((id < 0) ? 2.f : 0.f);
  int au = (id < 0) ? (-id - 1) : (id - 1);
  au = max(0, min(31, au));
  const float v = emb[(size_t)(b * 32 + au) * 1024 + w] * wt;
  if (isBF) ((u16*)outv)[idx] = f2bf(v);
  else      ((float*)outv)[idx] = v;
}

// ---------------------------------------------------------------------------
// ws layout (serial dirs; G reused):
//  fp32-G (ws >= 143,410,176; R5 proved >=176.7MB):
//    G 128Mi | Hhi 64Ki | Hlo 64Ki | mp 4Mi | emb 4Mi | twT 400Ki | biasT 512
//    | slots 256Ki (64 x 4KB spread) | flags 512   = 143,410,176 B
//  fp16-G fallback: G 64Mi + same tail = 76,301,312 B
// ---------------------------------------------------------------------------
extern "C" void kernel_launch(void* const* d_in, const int* in_sizes, int n_in,
                              void* d_out, int out_size, void* d_ws, size_t ws_size,
                              hipStream_t stream) {
  (void)in_sizes; (void)n_in; (void)out_size;
  const void* X    = d_in[0];
  const void* uid  = d_in[1];
  const void* Wihf = d_in[2];
  const void* Whhf = d_in[3];
  const void* bihf = d_in[4];
  const void* bhhf = d_in[5];
  const void* Wihb = d_in[6];
  const void* Whhb = d_in[7];
  const void* bihb = d_in[8];
  const void* bhhb = d_in[9];
  const void* tw   = d_in[10];
  const void* tb   = d_in[11];
  const void* tt   = d_in[12];
  char* ws = (char*)d_ws;

  const int gHalf = (ws_size >= 143410176ull) ? 0 : 1;
  const size_t gBytes = gHalf ? 67108864ull : 134217728ull;
  const size_t oHhi = gBytes;
  const size_t oHlo = oHhi + 65536ull;
  const size_t omp  = oHlo + 65536ull;
  const size_t oem  = omp + 4194304ull;
  const size_t otw  = oem + 4194304ull;
  const size_t obi  = otw + 409600ull;
  const size_t osl  = obi + 512ull;
  const size_t oFL  = osl + 262144ull;

  void*  G     = (void*)(ws + 0);
  u16*   Hhi   = (u16*)(ws + oHhi);
  u16*   Hlo   = (u16*)(ws + oHlo);
  float* mp    = (float*)(ws + omp);
  float* emb   = (float*)(ws + oem);
  float* twT   = (float*)(ws + otw);
  float* biasT = (float*)(ws + obi);
  u32*   slots = (u32*)(ws + osl);
  u32*   flags = (u32*)(ws + oFL);

  (void)hipMemsetAsync(mp, 0, 4194304ull, stream);    // segment-max floor = 0
  (void)hipMemsetAsync(slots, 0, 262144ull, stream);  // barrier slots (spread)
  k_probe<<<1, 256, 0, stream>>>((const u32*)X, (const u32*)uid, flags);

  // dir 0 (forward)
  k_xproj<<<dim3(256, 32), 256, 0, stream>>>(X, Wihf, bihf, bhhf, G, flags, gHalf);
  k_lstm<<<64, 256, 0, stream>>>(G, Whhf, Hhi, Hlo, mp, uid, slots, 0, flags, gHalf);
  // dir 1 (backward) — G reused (stream-ordered); slot targets offset +512
  k_xproj<<<dim3(256, 32), 256, 0, stream>>>(X, Wihb, bihb, bhhb, G, flags, gHalf);
  k_lstm<<<64, 256, 0, stream>>>(G, Whhb, Hhi, Hlo, mp, uid, slots, 1, flags, gHalf);

  k_prep<<<401, 256, 0, stream>>>(tw, tb, twT, biasT, flags);
  k_topic<<<1024, 256, 0, stream>>>(mp, twT, biasT, tt, emb, flags);
  k_out<<<65536, 256, 0, stream>>>(emb, uid, d_out, flags);
}

// Round 6
// 7357.790 us; speedup vs baseline: 2.7384x; 1.6430x over previous
//
#include <hip/hip_runtime.h>
#include <hip/hip_fp16.h>

// GetTopic: biLSTM (B=32,S=512,W=1024,HP=512) -> fused per-utterance segment
// max -> topic softmax (T=100) -> weighted gather. Inputs fp32 (probe kept).
//
// R12 vs R11 (12.1 ms; k_lstm 2x4.97 ms serial, step pinned ~9.7 us after
// 3 rounds of latency surgery): stop shortening the step, run BOTH dirs
// concurrently. G capacity solved by PHASING (no precision change):
//   phase A: xproj dir0 s[0,256) -> GA ; xproj dir1 s[256,512) -> GB ;
//            k_lstm2 (128 WGs: 64/dir, separate slot groups) t=0..255
//   phase B: xproj other halves ; k_lstm2 t=256..511
// c spills to ws across the phase boundary; h slabs + slot values carry
// (kernel boundary = barrier + visibility). Step mechanics verbatim R11:
// slot barrier (4KB spread, single-writer, relaxed sc1), sc1 h exchange,
// LDS-staged wave0 h stores, split-bf16 MFMA core, deferred mp atomicMax.

typedef unsigned short u16;
typedef unsigned int   u32;
typedef unsigned long long u64;
typedef __attribute__((ext_vector_type(8))) short short8;
typedef __attribute__((ext_vector_type(4))) float float4v;

__device__ __forceinline__ float bf2f(u16 u) { return __uint_as_float(((u32)u) << 16); }
__device__ __forceinline__ u16 f2bf(float f) {
  u32 u = __float_as_uint(f);
  u32 r = u + 0x7FFFu + ((u >> 16) & 1u);   // RNE
  return (u16)(r >> 16);
}
__device__ __forceinline__ float sigm(float x) { return 1.f / (1.f + expf(-x)); }

__device__ __forceinline__ float ldF(const void* p, size_t i, int isBF) {
  return isBF ? bf2f(((const u16*)p)[i]) : ((const float*)p)[i];
}
__device__ __forceinline__ int ldI(const void* p, int i, int is64) {
  return is64 ? (int)((const u32*)p)[(size_t)2 * i] : ((const int*)p)[i];
}

union U4S8 { uint4 u; short8 s; u16 us[8]; };

// ---------------------------------------------------------------------------
// Probe: input storage formats from raw bits (R4/R5-proven).
// flags[0]: 1 = float tensors bf16, 0 = fp32.  flags[1]: 1 = ids int64.
// ---------------------------------------------------------------------------
__global__ __launch_bounds__(256) void k_probe(
    const u32* __restrict__ X, const u32* __restrict__ U, u32* __restrict__ flags)
{
  __shared__ int cnt[2];
  if (threadIdx.x == 0) { cnt[0] = 0; cnt[1] = 0; }
  __syncthreads();
  int c0 = 0;
  for (int i = threadIdx.x; i < 1024; i += 256) {
    const u32 e = (X[i] >> 7) & 0xFFu;
    if (e >= 112u && e <= 143u) c0++;
  }
  int c1 = 0;
  {
    const u32 w = U[2 * threadIdx.x + 1];
    if (w == 0u || w == 0xFFFFFFFFu) c1++;
  }
  atomicAdd(&cnt[0], c0);
  atomicAdd(&cnt[1], c1);
  __syncthreads();
  if (threadIdx.x == 0) {
    flags[0] = (cnt[0] >= 512) ? 1u : 0u;
    flags[1] = (cnt[1] >= 128) ? 1u : 0u;
  }
}

// ---------------------------------------------------------------------------
// Phase 1: G_local[sl][n][b] = x[s0+sl] @ Wih^T + (bih+bhh) for sl in [0,256).
// GEMM M=8192 (m=sl*32+b), N=2048, K=1024. 64x64 tiles, 4x4/thread. (R5 core)
// ---------------------------------------------------------------------------
__global__ __launch_bounds__(256) void k_xproj(
    const void* __restrict__ X, const void* __restrict__ Wih,
    const void* __restrict__ bih, const void* __restrict__ bhh,
    void* __restrict__ Gv, const u32* __restrict__ flags, int gHalf, int s0)
{
  const int isBF = (int)flags[0];
  const int m0 = blockIdx.x * 64;
  const int n0 = blockIdx.y * 64;
  __shared__ float Asl[32][68];
  __shared__ float Bsl[32][68];
  const int tid = threadIdx.x;
  const int tx = tid & 15, ty = tid >> 4;
  const int lrow = tid >> 2;
  const int lkg  = (tid & 3) * 8;
  const int am = m0 + lrow;
  const int ab = am & 31, asl = am >> 5;           // m = sl*32 + b
  const size_t arow = ((size_t)ab * 512 + (s0 + asl)) * 1024;
  const size_t brow = (size_t)(n0 + lrow) * 1024;
  float acc[4][4] = {{0.f, 0.f, 0.f, 0.f}};
  for (int k0 = 0; k0 < 1024; k0 += 32) {
    float a8[8], b8[8];
    if (isBF) {
      const u16* Xh = (const u16*)X;
      const u16* Wh = (const u16*)Wih;
      uint4 va = *(const uint4*)(Xh + arow + k0 + lkg);
      uint4 vb = *(const uint4*)(Wh + brow + k0 + lkg);
      const u32 wa[4] = {va.x, va.y, va.z, va.w};
      const u32 wb[4] = {vb.x, vb.y, vb.z, vb.w};
#pragma unroll
      for (int q = 0; q < 4; ++q) {
        a8[2 * q]     = __uint_as_float(wa[q] << 16);
        a8[2 * q + 1] = __uint_as_float(wa[q] & 0xFFFF0000u);
        b8[2 * q]     = __uint_as_float(wb[q] << 16);
        b8[2 * q + 1] = __uint_as_float(wb[q] & 0xFFFF0000u);
      }
    } else {
      const float* Xf = (const float*)X;
      const float* Wf = (const float*)Wih;
      const float4 xa0 = *(const float4*)(Xf + arow + k0 + lkg);
      const float4 xa1 = *(const float4*)(Xf + arow + k0 + lkg + 4);
      const float4 xb0 = *(const float4*)(Wf + brow + k0 + lkg);
      const float4 xb1 = *(const float4*)(Wf + brow + k0 + lkg + 4);
      a8[0] = xa0.x; a8[1] = xa0.y; a8[2] = xa0.z; a8[3] = xa0.w;
      a8[4] = xa1.x; a8[5] = xa1.y; a8[6] = xa1.z; a8[7] = xa1.w;
      b8[0] = xb0.x; b8[1] = xb0.y; b8[2] = xb0.z; b8[3] = xb0.w;
      b8[4] = xb1.x; b8[5] = xb1.y; b8[6] = xb1.z; b8[7] = xb1.w;
    }
#pragma unroll
    for (int q = 0; q < 8; ++q) {
      Asl[lkg + q][lrow] = a8[q];
      Bsl[lkg + q][lrow] = b8[q];
    }
    __syncthreads();
#pragma unroll
    for (int k = 0; k < 32; ++k) {
      const float4 av = *(const float4*)&Asl[k][ty * 4];
      const float4 bv = *(const float4*)&Bsl[k][tx * 4];
      float a4[4] = {av.x, av.y, av.z, av.w};
      float b4[4] = {bv.x, bv.y, bv.z, bv.w};
#pragma unroll
      for (int i = 0; i < 4; ++i)
#pragma unroll
        for (int j = 0; j < 4; ++j)
          acc[i][j] = fmaf(a4[i], b4[j], acc[i][j]);
    }
    __syncthreads();
  }
  float bias[4];
#pragma unroll
  for (int j = 0; j < 4; ++j) {
    int n = n0 + tx * 4 + j;
    bias[j] = ldF(bih, n, isBF) + ldF(bhh, n, isBF);
  }
  const int mb = m0 + ty * 4;
  const int b0 = mb & 31, ss = mb >> 5;            // local sl
#pragma unroll
  for (int j = 0; j < 4; ++j) {
    const int n = n0 + tx * 4 + j;
    const size_t off = ((size_t)ss * 2048 + n) * 32 + b0;
    if (gHalf) {
      ushort4 pk;
      pk.x = __half_as_ushort(__float2half(acc[0][j] + bias[j]));
      pk.y = __half_as_ushort(__float2half(acc[1][j] + bias[j]));
      pk.z = __half_as_ushort(__float2half(acc[2][j] + bias[j]));
      pk.w = __half_as_ushort(__float2half(acc[3][j] + bias[j]));
      *(uint2*)((u16*)Gv + off) = *(uint2*)&pk;
    } else {
      float4 pk;
      pk.x = acc[0][j] + bias[j]; pk.y = acc[1][j] + bias[j];
      pk.z = acc[2][j] + bias[j]; pk.w = acc[3][j] + bias[j];
      *(float4*)((float*)Gv + off) = pk;
    }
  }
}

// ---------------------------------------------------------------------------
// Phase 2 body (R11-proven step mechanics + phasing). One dir, 64 WGs x 256.
// WG owns 8 hidden units = 32 gate cols; Whh resident as split-bf16 MFMA
// fragments (3 chains hh/hl/lh ~ fp32). h exchanged via sc1 ping-pong slabs.
// t in [t0,t1); G indexed locally: ls = dir ? 511-t-s0 : t-s0. c restored
// from / spilled to Cb across phase boundaries.
// ---------------------------------------------------------------------------
__device__ __forceinline__ void lstm_body(
    const int wg, const int dir, const int t0, const int t1, const int s0,
    const void* __restrict__ Gv, const void* __restrict__ Whh,
    u16* __restrict__ Hhi, u16* __restrict__ Hlo, float* __restrict__ Cb,
    float* __restrict__ mp, const void* __restrict__ uid,
    u32* __restrict__ slots, const u32* __restrict__ flags, const int gHalf)
{
  __shared__ float gl[1024];                    // [col32][b32] gate preacts
  __shared__ __align__(16) u16 shh[256];        // staged h hi: [b32][u8]
  __shared__ __align__(16) u16 shl[256];        // staged h lo: [b32][u8]
  const int isBF = (int)flags[0];
  const int is64 = (int)flags[1];
  const int tid = threadIdx.x;
  const int j0 = wg * 8;
  const int lane = tid & 63;
  const int wid = tid >> 6;
  const int mt = wid & 1, nt = wid >> 1;
  const int l15 = lane & 15;
  const int quad = lane >> 4;
  const int nl = nt * 16 + l15;        // col 0..31 within WG
  const int n = ((nl >> 3) * 512) + j0 + (nl & 7);   // global gate row/col

  // B-frags: split-bf16 of Whh row n. B[n=l15][k=quad*8+j].
  short8 bhi[16], blo[16];
#pragma unroll 1
  for (int kt = 0; kt < 16; ++kt) {
    const int k0 = kt * 32 + quad * 8;
    float w[8];
    if (isBF) {
      const u16* Wh = (const u16*)Whh;
#pragma unroll
      for (int jj = 0; jj < 8; ++jj) w[jj] = bf2f(Wh[(size_t)n * 512 + k0 + jj]);
    } else {
      const float* Wf = (const float*)Whh;
      const float4 w0 = *(const float4*)(Wf + (size_t)n * 512 + k0);
      const float4 w1 = *(const float4*)(Wf + (size_t)n * 512 + k0 + 4);
      w[0] = w0.x; w[1] = w0.y; w[2] = w0.z; w[3] = w0.w;
      w[4] = w1.x; w[5] = w1.y; w[6] = w1.z; w[7] = w1.w;
    }
    U4S8 ph, pl;
#pragma unroll
    for (int jj = 0; jj < 8; ++jj) {
      const u16 hi = f2bf(w[jj]);
      const float rem = w[jj] - bf2f(hi);   // exact (Sterbenz)
      ph.us[jj] = hi; pl.us[jj] = f2bf(rem);
    }
    bhi[kt] = ph.s; blo[kt] = pl.s;
  }

  const int b_a = mt * 16 + l15;        // A row = batch
  const int cb = tid & 31;              // consumer: batch
  const int ciu = tid >> 5;             // consumer: unit 0..7
  float c = (t0 == 0) ? 0.f : Cb[cb * 512 + j0 + ciu];

  // Per-thread G column offset; per-step local offset = ls*65536 + gcol.
  const size_t gcol = (size_t)n * 32 + (size_t)(mt * 16 + quad * 4);

  // Prefetch G for t=t0 (plain cached loads -- L2 stays warm).
  float4v gpre;
  {
    const int ls = dir ? (511 - t0 - s0) : (t0 - s0);
    const size_t goff = (size_t)ls * 65536 + gcol;
    if (gHalf) {
      const __half* Gp = (const __half*)Gv;
      gpre.x = __half2float(Gp[goff + 0]);
      gpre.y = __half2float(Gp[goff + 1]);
      gpre.z = __half2float(Gp[goff + 2]);
      gpre.w = __half2float(Gp[goff + 3]);
    } else {
      const float4 gv = *(const float4*)((const float*)Gv + goff);
      gpre.x = gv.x; gpre.y = gv.y; gpre.z = gv.z; gpre.w = gv.w;
    }
  }

  for (int t = t0; t < t1; ++t) {
    const int sidx = dir ? (511 - t) : t;
    if (t > t0) {
      // Parallel detection: lane i of wave 0 polls slot i (4KB spread).
      // Single-writer slots, relaxed sc1 loads, no cache maintenance.
      if (tid < 64) {
        const u32 target = (u32)t;
        const u32* sl = slots + (size_t)lane * 1024;   // 4KB stride
        for (;;) {
          const u32 v = __hip_atomic_load(sl, __ATOMIC_RELAXED, __HIP_MEMORY_SCOPE_AGENT);
          if (__all((int)(v >= target))) break;
          __builtin_amdgcn_s_sleep(1);
        }
      }
      __syncthreads();
    }

    // C-init from prefetched G (4 consecutive batches per lane, col n).
    float4v acc_hh = gpre;
    float4v acc_hl, acc_lh;
    acc_hl.x = 0.f; acc_hl.y = 0.f; acc_hl.z = 0.f; acc_hl.w = 0.f;
    acc_lh.x = 0.f; acc_lh.y = 0.f; acc_lh.z = 0.f; acc_lh.w = 0.f;

    if (t > 0) {
      const size_t abase = (size_t)((t - 1) & 1) * 16384 + (size_t)b_a * 512 + quad * 8;
      const u16* ah = Hhi + abase;
      const u16* al = Hlo + abase;
      // Issue all 32 sc1 (MALL-coherent) 16B loads, then one wait.
      U4S8 va[16], vl[16];
#pragma unroll
      for (int kt = 0; kt < 16; ++kt) {
        asm volatile(
            "global_load_dwordx4 %0, %2, off offset:%4 sc1\n\t"
            "global_load_dwordx4 %1, %3, off offset:%4 sc1"
            : "=v"(va[kt].u), "=v"(vl[kt].u)
            : "v"(ah), "v"(al), "i"(kt * 64)
            : "memory");
      }
      asm volatile("s_waitcnt vmcnt(0)" ::: "memory");
      __builtin_amdgcn_sched_barrier(0);
#pragma unroll
      for (int kt = 0; kt < 16; ++kt) {
        acc_hh = __builtin_amdgcn_mfma_f32_16x16x32_bf16(va[kt].s, bhi[kt], acc_hh, 0, 0, 0);
        acc_hl = __builtin_amdgcn_mfma_f32_16x16x32_bf16(va[kt].s, blo[kt], acc_hl, 0, 0, 0);
        acc_lh = __builtin_amdgcn_mfma_f32_16x16x32_bf16(vl[kt].s, bhi[kt], acc_lh, 0, 0, 0);
      }
    }

    // Prefetch next step's G (independent; hides under exchange + barrier).
    if (t + 1 < t1) {
      const int ls = dir ? (511 - (t + 1) - s0) : (t + 1 - s0);
      const size_t goff = (size_t)ls * 65536 + gcol;
      if (gHalf) {
        const __half* Gp = (const __half*)Gv;
        gpre.x = __half2float(Gp[goff + 0]);
        gpre.y = __half2float(Gp[goff + 1]);
        gpre.z = __half2float(Gp[goff + 2]);
        gpre.w = __half2float(Gp[goff + 3]);
      } else {
        const float4 gv = *(const float4*)((const float*)Gv + goff);
        gpre.x = gv.x; gpre.y = gv.y; gpre.z = gv.z; gpre.w = gv.w;
      }
    }

    // exchange: D row (quad*4+r) = batch - mt*16, col l15 -> nl
    {
      const int base = nl * 32 + mt * 16 + quad * 4;
      gl[base + 0] = acc_hh.x + acc_hl.x + acc_lh.x;
      gl[base + 1] = acc_hh.y + acc_hl.y + acc_lh.y;
      gl[base + 2] = acc_hh.z + acc_hl.z + acc_lh.z;
      gl[base + 3] = acc_hh.w + acc_hl.w + acc_lh.w;
    }
    __syncthreads();

    float hval;
    int id;
    {
      const float a0 = gl[(0 * 8 + ciu) * 32 + cb];
      const float a1 = gl[(1 * 8 + ciu) * 32 + cb];
      const float a2 = gl[(2 * 8 + ciu) * 32 + cb];
      const float a3 = gl[(3 * 8 + ciu) * 32 + cb];
      const float ig = sigm(a0), fg = sigm(a1);
      const float gg = tanhf(a2), og = sigm(a3);
      c = fg * c + ig * gg;
      hval = og * tanhf(c);
      const u16 hh = f2bf(hval);
      shh[cb * 8 + ciu] = hh;
      shl[cb * 8 + ciu] = f2bf(hval - bf2f(hh));
      id = ldI(uid, cb * 512 + sidx, is64);
    }
    __syncthreads();

    // Wave 0: re-gather staged h, 128x 8B agent stores (16B runs per batch),
    // one drain, tid0 publishes. Other waves proceed to atomicMax.
    if (tid < 64) {
      const int sb = lane >> 1, q = lane & 1;       // batch, 4-unit chunk
      const u64 vh = ((const u64*)shh)[sb * 2 + q];
      const u64 vo = ((const u64*)shl)[sb * 2 + q];
      const size_t so = (size_t)(t & 1) * 16384 + (size_t)sb * 512 + j0 + q * 4;
      __hip_atomic_store((u64*)(Hhi + so), vh, __ATOMIC_RELAXED, __HIP_MEMORY_SCOPE_AGENT);
      __hip_atomic_store((u64*)(Hlo + so), vo, __ATOMIC_RELAXED, __HIP_MEMORY_SCOPE_AGENT);
      asm volatile("s_waitcnt vmcnt(0)" ::: "memory");
      if (tid == 0)
        __hip_atomic_store(slots + (size_t)wg * 1024, (u32)(t + 1),
                           __ATOMIC_RELAXED, __HIP_MEMORY_SCOPE_AGENT);
    }
    // Deferred fused max-pool: overlaps the next poll. Visible to k_topic via
    // end-of-kernel release.
    if (id > 0 && hval > 0.f)
      atomicMax((int*)&mp[(size_t)(cb * 32 + (id - 1)) * 1024 + dir * 512 + (j0 + ciu)],
                __float_as_int(hval));
  }

  if (t1 < 512) Cb[cb * 512 + j0 + ciu] = c;   // spill c across phase boundary
}

// Fused dual-direction phase kernel: WGs 0..63 = dir0, 64..127 = dir1.
// Dirs are independent recurrences: separate G, Whh, h slabs, c spill,
// slot groups. mp shared (atomicMax, disjoint halves via dir*512).
__global__ __launch_bounds__(256) void k_lstm2(
    const void* __restrict__ GA, const void* __restrict__ GB,
    const void* __restrict__ WhhA, const void* __restrict__ WhhB,
    u16* __restrict__ Hh0, u16* __restrict__ Hl0,
    u16* __restrict__ Hh1, u16* __restrict__ Hl1,
    float* __restrict__ Cb, float* __restrict__ mp,
    const void* __restrict__ uid, u32* __restrict__ slots,
    const u32* __restrict__ flags, int gHalf,
    int t0, int t1, int s0A, int s0B)
{
  const int dir = ((int)blockIdx.x >= 64) ? 1 : 0;
  const int wg = (int)blockIdx.x & 63;
  const void* Gv  = dir ? GB : GA;
  const void* Whh = dir ? WhhB : WhhA;
  u16* Hhi = dir ? Hh1 : Hh0;
  u16* Hlo = dir ? Hl1 : Hl0;
  lstm_body(wg, dir, t0, t1, dir ? s0B : s0A, Gv, Whh, Hhi, Hlo,
            Cb + (size_t)dir * 16384, mp, uid,
            slots + (size_t)dir * 65536, flags, gHalf);
}

// ---------------------------------------------------------------------------
// Phase 4a: topic_weights -> twT[k][t] fp32, bias -> fp32.
// ---------------------------------------------------------------------------
__global__ __launch_bounds__(256) void k_prep(
    const void* __restrict__ tw, const void* __restrict__ tb,
    float* __restrict__ twT, float* __restrict__ biasT, const u32* __restrict__ flags)
{
  const int isBF = (int)flags[0];
  const int idx = blockIdx.x * 256 + threadIdx.x;
  if (idx < 102400) {
    const int t = idx >> 10, k = idx & 1023;
    twT[k * 100 + t] = ldF(tw, idx, isBF);
  } else if (idx < 102500) {
    biasT[idx - 102400] = ldF(tb, idx - 102400, isBF);
  }
}

// ---------------------------------------------------------------------------
// Phase 4: per (b,u): logits(100) -> softmax -> emb row (fp32).
// ---------------------------------------------------------------------------
__global__ __launch_bounds__(256) void k_topic(
    const float* __restrict__ mp, const float* __restrict__ twT,
    const float* __restrict__ biasT, const void* __restrict__ table,
    float* __restrict__ emb, const u32* __restrict__ flags)
{
  const int isBF = (int)flags[0];
  const int bu = blockIdx.x;
  const int tid = threadIdx.x;
  __shared__ float lrow[1024];
  __shared__ float red[128];
  __shared__ float parr[128];
  for (int i = tid; i < 1024; i += 256) lrow[i] = mp[(size_t)bu * 1024 + i];
  __syncthreads();
  float lacc = -1e30f;
  if (tid < 100) {
    lacc = biasT[tid];
    for (int k = 0; k < 1024; ++k) lacc = fmaf(lrow[k], twT[k * 100 + tid], lacc);
  }
  if (tid < 128) red[tid] = (tid < 100) ? lacc : -1e30f;
  __syncthreads();
  for (int off = 64; off > 0; off >>= 1) {
    if (tid < off) red[tid] = fmaxf(red[tid], red[tid + off]);
    __syncthreads();
  }
  const float mxv = red[0];
  __syncthreads();
  const float e = (tid < 100) ? expf(lacc - mxv) : 0.f;
  if (tid < 128) red[tid] = e;
  __syncthreads();
  for (int off = 64; off > 0; off >>= 1) {
    if (tid < off) red[tid] += red[tid + off];
    __syncthreads();
  }
  const float inv = 1.f / red[0];
  if (tid < 128) parr[tid] = e * inv;
  __syncthreads();
#pragma unroll
  for (int r = 0; r < 4; ++r) {
    const int w = tid + 256 * r;
    float a = 0.f;
    for (int t = 0; t < 100; ++t)
      a = fmaf(parr[t], ldF(table, (size_t)t * 1024 + w, isBF), a);
    emb[(size_t)bu * 1024 + w] = a;
  }
}

// ---------------------------------------------------------------------------
// Phase 5: out = emb[b][clip(|uid|-1,0,31)][w] * {1,2,0}. Dtype by flag.
// ---------------------------------------------------------------------------
__global__ __launch_bounds__(256) void k_out(
    const float* __restrict__ emb, const void* __restrict__ uid,
    void* __restrict__ outv, const u32* __restrict__ flags)
{
  const int isBF = (int)flags[0];
  const int is64 = (int)flags[1];
  const int idx = blockIdx.x * 256 + threadIdx.x;
  const int w = idx & 1023;
  const int s = (idx >> 10) & 511;
  const int b = idx >> 19;
  const int id = ldI(uid, b * 512 + s, is64);
  const float wt = (id > 0) ? 1.f : ((id < 0) ? 2.f : 0.f);
  int au = (id < 0) ? (-id - 1) : (id - 1);
  au = max(0, min(31, au));
  const float v = emb[(size_t)(b * 32 + au) * 1024 + w] * wt;
  if (isBF) ((u16*)outv)[idx] = f2bf(v);
  else      ((float*)outv)[idx] = v;
}

// ---------------------------------------------------------------------------
// ws layout (phased fused dirs):
//  fp32-G (ws >= 143,934,464; R5 proved >=176.7MB):
//    GA 64Mi | GB 64Mi | Hh0,Hl0,Hh1,Hl1 4x64Ki | Cb 128Ki | mp 4Mi | emb 4Mi
//    | twT 400Ki | biasT 512 | slots 512Ki (128 x 4KB spread) | flags 512
//  fp16-G fallback: GA/GB 32Mi each + same tail ~= 76.8 MB
// ---------------------------------------------------------------------------
extern "C" void kernel_launch(void* const* d_in, const int* in_sizes, int n_in,
                              void* d_out, int out_size, void* d_ws, size_t ws_size,
                              hipStream_t stream) {
  (void)in_sizes; (void)n_in; (void)out_size;
  const void* X    = d_in[0];
  const void* uid  = d_in[1];
  const void* Wihf = d_in[2];
  const void* Whhf = d_in[3];
  const void* bihf = d_in[4];
  const void* bhhf = d_in[5];
  const void* Wihb = d_in[6];
  const void* Whhb = d_in[7];
  const void* bihb = d_in[8];
  const void* bhhb = d_in[9];
  const void* tw   = d_in[10];
  const void* tb   = d_in[11];
  const void* tt   = d_in[12];
  char* ws = (char*)d_ws;

  const int gHalf = (ws_size >= 143934464ull) ? 0 : 1;
  const size_t gB = gHalf ? 33554432ull : 67108864ull;   // per-dir G (256 steps)
  const size_t oGB = gB;
  const size_t oH  = 2ull * gB;
  const size_t oCb = oH + 262144ull;          // 4 slabs x 64Ki
  const size_t omp = oCb + 131072ull;
  const size_t oem = omp + 4194304ull;
  const size_t otw = oem + 4194304ull;
  const size_t obi = otw + 409600ull;
  const size_t osl = obi + 512ull;
  const size_t oFL = osl + 524288ull;

  void*  GA    = (void*)(ws + 0);
  void*  GB    = (void*)(ws + oGB);
  u16*   Hh0   = (u16*)(ws + oH);
  u16*   Hl0   = (u16*)(ws + oH + 65536ull);
  u16*   Hh1   = (u16*)(ws + oH + 131072ull);
  u16*   Hl1   = (u16*)(ws + oH + 196608ull);
  float* Cb    = (float*)(ws + oCb);
  float* mp    = (float*)(ws + omp);
  float* emb   = (float*)(ws + oem);
  float* twT   = (float*)(ws + otw);
  float* biasT = (float*)(ws + obi);
  u32*   slots = (u32*)(ws + osl);
  u32*   flags = (u32*)(ws + oFL);

  (void)hipMemsetAsync(mp, 0, 4194304ull, stream);    // segment-max floor = 0
  (void)hipMemsetAsync(slots, 0, 524288ull, stream);  // barrier slots (spread)
  k_probe<<<1, 256, 0, stream>>>((const u32*)X, (const u32*)uid, flags);

  // Phase A: dir0 s[0,256) -> GA; dir1 s[256,512) -> GB; steps t=0..255.
  k_xproj<<<dim3(128, 32), 256, 0, stream>>>(X, Wihf, bihf, bhhf, GA, flags, gHalf, 0);
  k_xproj<<<dim3(128, 32), 256, 0, stream>>>(X, Wihb, bihb, bhhb, GB, flags, gHalf, 256);
  k_lstm2<<<128, 256, 0, stream>>>(GA, GB, Whhf, Whhb, Hh0, Hl0, Hh1, Hl1,
                                   Cb, mp, uid, slots, flags, gHalf,
                                   0, 256, 0, 256);
  // Phase B: dir0 s[256,512) -> GA; dir1 s[0,256) -> GB; steps t=256..511.
  k_xproj<<<dim3(128, 32), 256, 0, stream>>>(X, Wihf, bihf, bhhf, GA, flags, gHalf, 256);
  k_xproj<<<dim3(128, 32), 256, 0, stream>>>(X, Wihb, bihb, bhhb, GB, flags, gHalf, 0);
  k_lstm2<<<128, 256, 0, stream>>>(GA, GB, Whhf, Whhb, Hh0, Hl0, Hh1, Hl1,
                                   Cb, mp, uid, slots, flags, gHalf,
                                   256, 512, 256, 0);

  k_prep<<<401, 256, 0, stream>>>(tw, tb, twT, biasT, flags);
  k_topic<<<1024, 256, 0, stream>>>(mp, twT, biasT, tt, emb, flags);
  k_out<<<65536, 256, 0, stream>>>(emb, uid, d_out, flags);
}

// Round 8
// 5787.045 us; speedup vs baseline: 3.4816x; 1.2714x over previous
//
#include <hip/hip_runtime.h>
#include <hip/hip_fp16.h>

// GetTopic: biLSTM (B=32,S=512,W=1024,HP=512) -> fused per-utterance segment
// max -> topic softmax (T=100) -> weighted gather. Inputs fp32 (probe kept).
//
// R14 = R12 (7.36 ms, PROVEN) + ONE delta: k_xproj MFMA-ized (split-bf16
// hi/lo 3-chain 16x16x32, the exact numerics + lane mapping proven in the
// recurrence core). R13's second delta (LDS mp stripe) is DROPPED - R13
// aborted and the mp stripe is the only unproven memory path; mp max-pool
// stays as R12's deferred atomicMax.
// Everything else verbatim R12: phased dual-dir k_lstm2 (2x256 steps, c
// spilled across phases), slot barrier (4KB spread, single-writer, relaxed
// sc1), sc1 h exchange, LDS-staged wave0 h stores, split-bf16 MFMA core.

typedef unsigned short u16;
typedef unsigned int   u32;
typedef unsigned long long u64;
typedef __attribute__((ext_vector_type(8))) short short8;
typedef __attribute__((ext_vector_type(4))) float float4v;

__device__ __forceinline__ float bf2f(u16 u) { return __uint_as_float(((u32)u) << 16); }
__device__ __forceinline__ u16 f2bf(float f) {
  u32 u = __float_as_uint(f);
  u32 r = u + 0x7FFFu + ((u >> 16) & 1u);   // RNE
  return (u16)(r >> 16);
}
__device__ __forceinline__ float sigm(float x) { return 1.f / (1.f + expf(-x)); }

__device__ __forceinline__ float ldF(const void* p, size_t i, int isBF) {
  return isBF ? bf2f(((const u16*)p)[i]) : ((const float*)p)[i];
}
__device__ __forceinline__ int ldI(const void* p, int i, int is64) {
  return is64 ? (int)((const u32*)p)[(size_t)2 * i] : ((const int*)p)[i];
}

union U4S8 { uint4 u; short8 s; u16 us[8]; };

// ---------------------------------------------------------------------------
// Probe: input storage formats from raw bits (R4/R5-proven).
// flags[0]: 1 = float tensors bf16, 0 = fp32.  flags[1]: 1 = ids int64.
// ---------------------------------------------------------------------------
__global__ __launch_bounds__(256) void k_probe(
    const u32* __restrict__ X, const u32* __restrict__ U, u32* __restrict__ flags)
{
  __shared__ int cnt[2];
  if (threadIdx.x == 0) { cnt[0] = 0; cnt[1] = 0; }
  __syncthreads();
  int c0 = 0;
  for (int i = threadIdx.x; i < 1024; i += 256) {
    const u32 e = (X[i] >> 7) & 0xFFu;
    if (e >= 112u && e <= 143u) c0++;
  }
  int c1 = 0;
  {
    const u32 w = U[2 * threadIdx.x + 1];
    if (w == 0u || w == 0xFFFFFFFFu) c1++;
  }
  atomicAdd(&cnt[0], c0);
  atomicAdd(&cnt[1], c1);
  __syncthreads();
  if (threadIdx.x == 0) {
    flags[0] = (cnt[0] >= 512) ? 1u : 0u;
    flags[1] = (cnt[1] >= 128) ? 1u : 0u;
  }
}

// ---------------------------------------------------------------------------
// Phase 1: G_local[sl][n][b] = x[s0+sl] @ Wih^T + (bih+bhh) for sl in [0,256).
// R14: split-bf16 MFMA GEMM. M=8192 (m=sl*32+b), N=2048, K=1024.
// 64x64 tile / WG (256 thr, 4 waves). Wave w owns M-chunk w*16; computes 4
// 16x16 N-tiles; 3 MFMA chains (hh,hl,lh) accumulate into one fp32 acc.
// Global addressing identical to R12's proven kernel; LDS 4x 64x40 bf16.
// ---------------------------------------------------------------------------
__global__ __launch_bounds__(256) void k_xproj(
    const void* __restrict__ X, const void* __restrict__ Wih,
    const void* __restrict__ bih, const void* __restrict__ bhh,
    void* __restrict__ Gv, const u32* __restrict__ flags, int gHalf, int s0)
{
  const int isBF = (int)flags[0];
  const int m0 = blockIdx.x * 64;
  const int n0 = blockIdx.y * 64;
  __shared__ u16 Ah[64][40];   // stride 40 u16 (80B)
  __shared__ u16 Al[64][40];
  __shared__ u16 Bh[64][40];
  __shared__ u16 Bl[64][40];
  const int tid = threadIdx.x;
  const int lrow = tid >> 2;          // 0..63: staging row
  const int lkg  = (tid & 3) * 8;     // k-group of 8 within 32-wide k-tile
  const int lane = tid & 63;
  const int wid  = tid >> 6;          // wave -> M-chunk
  const int l15  = lane & 15;
  const int quad = lane >> 4;
  const int am = m0 + lrow;
  const int ab = am & 31, asl = am >> 5;           // m = sl*32 + b
  const size_t arow = ((size_t)ab * 512 + (s0 + asl)) * 1024;
  const size_t brow = (size_t)(n0 + lrow) * 1024;

  float4v acc[4];
#pragma unroll
  for (int c = 0; c < 4; ++c) {
    acc[c].x = 0.f; acc[c].y = 0.f; acc[c].z = 0.f; acc[c].w = 0.f;
  }

  for (int k0 = 0; k0 < 1024; k0 += 32) {
    float a8[8], b8[8];
    if (isBF) {
      const u16* Xh = (const u16*)X;
      const u16* Wh = (const u16*)Wih;
      uint4 va = *(const uint4*)(Xh + arow + k0 + lkg);
      uint4 vb = *(const uint4*)(Wh + brow + k0 + lkg);
      const u32 wa[4] = {va.x, va.y, va.z, va.w};
      const u32 wb[4] = {vb.x, vb.y, vb.z, vb.w};
#pragma unroll
      for (int q = 0; q < 4; ++q) {
        a8[2 * q]     = __uint_as_float(wa[q] << 16);
        a8[2 * q + 1] = __uint_as_float(wa[q] & 0xFFFF0000u);
        b8[2 * q]     = __uint_as_float(wb[q] << 16);
        b8[2 * q + 1] = __uint_as_float(wb[q] & 0xFFFF0000u);
      }
    } else {
      const float* Xf = (const float*)X;
      const float* Wf = (const float*)Wih;
      const float4 xa0 = *(const float4*)(Xf + arow + k0 + lkg);
      const float4 xa1 = *(const float4*)(Xf + arow + k0 + lkg + 4);
      const float4 xb0 = *(const float4*)(Wf + brow + k0 + lkg);
      const float4 xb1 = *(const float4*)(Wf + brow + k0 + lkg + 4);
      a8[0] = xa0.x; a8[1] = xa0.y; a8[2] = xa0.z; a8[3] = xa0.w;
      a8[4] = xa1.x; a8[5] = xa1.y; a8[6] = xa1.z; a8[7] = xa1.w;
      b8[0] = xb0.x; b8[1] = xb0.y; b8[2] = xb0.z; b8[3] = xb0.w;
      b8[4] = xb1.x; b8[5] = xb1.y; b8[6] = xb1.z; b8[7] = xb1.w;
    }
    // split to hi/lo bf16 (Sterbenz-exact remainder) and stage in LDS
    U4S8 pah, pal, pbh, pbl;
#pragma unroll
    for (int j = 0; j < 8; ++j) {
      const u16 ah = f2bf(a8[j]);
      pah.us[j] = ah; pal.us[j] = f2bf(a8[j] - bf2f(ah));
      const u16 bh = f2bf(b8[j]);
      pbh.us[j] = bh; pbl.us[j] = f2bf(b8[j] - bf2f(bh));
    }
    *(uint4*)&Ah[lrow][lkg] = pah.u;
    *(uint4*)&Al[lrow][lkg] = pal.u;
    *(uint4*)&Bh[lrow][lkg] = pbh.u;
    *(uint4*)&Bl[lrow][lkg] = pbl.u;
    __syncthreads();

    // Fragments: operand rows indexed by l15, k = quad*8 (recurrence-proven
    // mapping). A rows = M side (wave's 16-chunk), B rows = N side.
    U4S8 fah, fal;
    fah.u = *(const uint4*)&Ah[wid * 16 + l15][quad * 8];
    fal.u = *(const uint4*)&Al[wid * 16 + l15][quad * 8];
#pragma unroll
    for (int c = 0; c < 4; ++c) {
      U4S8 fbh, fbl;
      fbh.u = *(const uint4*)&Bh[c * 16 + l15][quad * 8];
      fbl.u = *(const uint4*)&Bl[c * 16 + l15][quad * 8];
      acc[c] = __builtin_amdgcn_mfma_f32_16x16x32_bf16(fah.s, fbh.s, acc[c], 0, 0, 0);
      acc[c] = __builtin_amdgcn_mfma_f32_16x16x32_bf16(fah.s, fbl.s, acc[c], 0, 0, 0);
      acc[c] = __builtin_amdgcn_mfma_f32_16x16x32_bf16(fal.s, fbh.s, acc[c], 0, 0, 0);
    }
    __syncthreads();
  }

  // Epilogue: D col = l15 (N side, chunk c), rows = quad*4+r (M side).
  // M rows map to b (batch) consecutively within one sl: b0 in {0,4,..,28}.
  const int mrow = m0 + wid * 16 + quad * 4;
  const int b0 = mrow & 31, sl = mrow >> 5;
#pragma unroll
  for (int c = 0; c < 4; ++c) {
    const int n = n0 + c * 16 + l15;
    const float bias = ldF(bih, n, isBF) + ldF(bhh, n, isBF);
    const size_t off = ((size_t)sl * 2048 + n) * 32 + b0;
    if (gHalf) {
      ushort4 pk;
      pk.x = __half_as_ushort(__float2half(acc[c].x + bias));
      pk.y = __half_as_ushort(__float2half(acc[c].y + bias));
      pk.z = __half_as_ushort(__float2half(acc[c].z + bias));
      pk.w = __half_as_ushort(__float2half(acc[c].w + bias));
      *(uint2*)((u16*)Gv + off) = *(uint2*)&pk;
    } else {
      float4 pk;
      pk.x = acc[c].x + bias; pk.y = acc[c].y + bias;
      pk.z = acc[c].z + bias; pk.w = acc[c].w + bias;
      *(float4*)((float*)Gv + off) = pk;
    }
  }
}

// ---------------------------------------------------------------------------
// Phase 2 body (R12-proven, VERBATIM). One dir, 64 WGs x 256. WG owns 8
// hidden units = 32 gate cols; Whh resident as split-bf16 MFMA fragments
// (3 chains hh/hl/lh ~ fp32). h exchanged via sc1 ping-pong slabs. t in
// [t0,t1); c restored/spilled across phase boundaries.
// ---------------------------------------------------------------------------
__device__ __forceinline__ void lstm_body(
    const int wg, const int dir, const int t0, const int t1, const int s0,
    const void* __restrict__ Gv, const void* __restrict__ Whh,
    u16* __restrict__ Hhi, u16* __restrict__ Hlo, float* __restrict__ Cb,
    float* __restrict__ mp, const void* __restrict__ uid,
    u32* __restrict__ slots, const u32* __restrict__ flags, const int gHalf)
{
  __shared__ float gl[1024];                    // [col32][b32] gate preacts
  __shared__ __align__(16) u16 shh[256];        // staged h hi: [b32][u8]
  __shared__ __align__(16) u16 shl[256];        // staged h lo: [b32][u8]
  const int isBF = (int)flags[0];
  const int is64 = (int)flags[1];
  const int tid = threadIdx.x;
  const int j0 = wg * 8;
  const int lane = tid & 63;
  const int wid = tid >> 6;
  const int mt = wid & 1, nt = wid >> 1;
  const int l15 = lane & 15;
  const int quad = lane >> 4;
  const int nl = nt * 16 + l15;        // col 0..31 within WG
  const int n = ((nl >> 3) * 512) + j0 + (nl & 7);   // global gate row/col

  // B-frags: split-bf16 of Whh row n. B[n=l15][k=quad*8+j].
  short8 bhi[16], blo[16];
#pragma unroll 1
  for (int kt = 0; kt < 16; ++kt) {
    const int k0 = kt * 32 + quad * 8;
    float w[8];
    if (isBF) {
      const u16* Wh = (const u16*)Whh;
#pragma unroll
      for (int jj = 0; jj < 8; ++jj) w[jj] = bf2f(Wh[(size_t)n * 512 + k0 + jj]);
    } else {
      const float* Wf = (const float*)Whh;
      const float4 w0 = *(const float4*)(Wf + (size_t)n * 512 + k0);
      const float4 w1 = *(const float4*)(Wf + (size_t)n * 512 + k0 + 4);
      w[0] = w0.x; w[1] = w0.y; w[2] = w0.z; w[3] = w0.w;
      w[4] = w1.x; w[5] = w1.y; w[6] = w1.z; w[7] = w1.w;
    }
    U4S8 ph, pl;
#pragma unroll
    for (int jj = 0; jj < 8; ++jj) {
      const u16 hi = f2bf(w[jj]);
      const float rem = w[jj] - bf2f(hi);   // exact (Sterbenz)
      ph.us[jj] = hi; pl.us[jj] = f2bf(rem);
    }
    bhi[kt] = ph.s; blo[kt] = pl.s;
  }

  const int b_a = mt * 16 + l15;        // A row = batch
  const int cb = tid & 31;              // consumer: batch
  const int ciu = tid >> 5;             // consumer: unit 0..7
  float c = (t0 == 0) ? 0.f : Cb[cb * 512 + j0 + ciu];

  // Per-thread G column offset; per-step local offset = ls*65536 + gcol.
  const size_t gcol = (size_t)n * 32 + (size_t)(mt * 16 + quad * 4);

  // Prefetch G for t=t0 (plain cached loads -- L2 stays warm).
  float4v gpre;
  {
    const int ls = dir ? (511 - t0 - s0) : (t0 - s0);
    const size_t goff = (size_t)ls * 65536 + gcol;
    if (gHalf) {
      const __half* Gp = (const __half*)Gv;
      gpre.x = __half2float(Gp[goff + 0]);
      gpre.y = __half2float(Gp[goff + 1]);
      gpre.z = __half2float(Gp[goff + 2]);
      gpre.w = __half2float(Gp[goff + 3]);
    } else {
      const float4 gv = *(const float4*)((const float*)Gv + goff);
      gpre.x = gv.x; gpre.y = gv.y; gpre.z = gv.z; gpre.w = gv.w;
    }
  }

  for (int t = t0; t < t1; ++t) {
    const int sidx = dir ? (511 - t) : t;
    if (t > t0) {
      // Parallel detection: lane i of wave 0 polls slot i (4KB spread).
      // Single-writer slots, relaxed sc1 loads, no cache maintenance.
      if (tid < 64) {
        const u32 target = (u32)t;
        const u32* sl = slots + (size_t)lane * 1024;   // 4KB stride
        for (;;) {
          const u32 v = __hip_atomic_load(sl, __ATOMIC_RELAXED, __HIP_MEMORY_SCOPE_AGENT);
          if (__all((int)(v >= target))) break;
          __builtin_amdgcn_s_sleep(1);
        }
      }
      __syncthreads();
    }

    // C-init from prefetched G (4 consecutive batches per lane, col n).
    float4v acc_hh = gpre;
    float4v acc_hl, acc_lh;
    acc_hl.x = 0.f; acc_hl.y = 0.f; acc_hl.z = 0.f; acc_hl.w = 0.f;
    acc_lh.x = 0.f; acc_lh.y = 0.f; acc_lh.z = 0.f; acc_lh.w = 0.f;

    if (t > 0) {
      const size_t abase = (size_t)((t - 1) & 1) * 16384 + (size_t)b_a * 512 + quad * 8;
      const u16* ah = Hhi + abase;
      const u16* al = Hlo + abase;
      // Issue all 32 sc1 (MALL-coherent) 16B loads, then one wait.
      U4S8 va[16], vl[16];
#pragma unroll
      for (int kt = 0; kt < 16; ++kt) {
        asm volatile(
            "global_load_dwordx4 %0, %2, off offset:%4 sc1\n\t"
            "global_load_dwordx4 %1, %3, off offset:%4 sc1"
            : "=v"(va[kt].u), "=v"(vl[kt].u)
            : "v"(ah), "v"(al), "i"(kt * 64)
            : "memory");
      }
      asm volatile("s_waitcnt vmcnt(0)" ::: "memory");
      __builtin_amdgcn_sched_barrier(0);
#pragma unroll
      for (int kt = 0; kt < 16; ++kt) {
        acc_hh = __builtin_amdgcn_mfma_f32_16x16x32_bf16(va[kt].s, bhi[kt], acc_hh, 0, 0, 0);
        acc_hl = __builtin_amdgcn_mfma_f32_16x16x32_bf16(va[kt].s, blo[kt], acc_hl, 0, 0, 0);
        acc_lh = __builtin_amdgcn_mfma_f32_16x16x32_bf16(vl[kt].s, bhi[kt], acc_lh, 0, 0, 0);
      }
    }

    // Prefetch next step's G (independent; hides under exchange + barrier).
    if (t + 1 < t1) {
      const int ls = dir ? (511 - (t + 1) - s0) : (t + 1 - s0);
      const size_t goff = (size_t)ls * 65536 + gcol;
      if (gHalf) {
        const __half* Gp = (const __half*)Gv;
        gpre.x = __half2float(Gp[goff + 0]);
        gpre.y = __half2float(Gp[goff + 1]);
        gpre.z = __half2float(Gp[goff + 2]);
        gpre.w = __half2float(Gp[goff + 3]);
      } else {
        const float4 gv = *(const float4*)((const float*)Gv + goff);
        gpre.x = gv.x; gpre.y = gv.y; gpre.z = gv.z; gpre.w = gv.w;
      }
    }

    // exchange: D row (quad*4+r) = batch - mt*16, col l15 -> nl
    {
      const int base = nl * 32 + mt * 16 + quad * 4;
      gl[base + 0] = acc_hh.x + acc_hl.x + acc_lh.x;
      gl[base + 1] = acc_hh.y + acc_hl.y + acc_lh.y;
      gl[base + 2] = acc_hh.z + acc_hl.z + acc_lh.z;
      gl[base + 3] = acc_hh.w + acc_hl.w + acc_lh.w;
    }
    __syncthreads();

    float hval;
    int id;
    {
      const float a0 = gl[(0 * 8 + ciu) * 32 + cb];
      const float a1 = gl[(1 * 8 + ciu) * 32 + cb];
      const float a2 = gl[(2 * 8 + ciu) * 32 + cb];
      const float a3 = gl[(3 * 8 + ciu) * 32 + cb];
      const float ig = sigm(a0), fg = sigm(a1);
      const float gg = tanhf(a2), og = sigm(a3);
      c = fg * c + ig * gg;
      hval = og * tanhf(c);
      const u16 hh = f2bf(hval);
      shh[cb * 8 + ciu] = hh;
      shl[cb * 8 + ciu] = f2bf(hval - bf2f(hh));
      id = ldI(uid, cb * 512 + sidx, is64);
    }
    __syncthreads();

    // Wave 0: re-gather staged h, 128x 8B agent stores (16B runs per batch),
    // one drain, tid0 publishes. Other waves proceed to atomicMax.
    if (tid < 64) {
      const int sb = lane >> 1, q = lane & 1;       // batch, 4-unit chunk
      const u64 vh = ((const u64*)shh)[sb * 2 + q];
      const u64 vo = ((const u64*)shl)[sb * 2 + q];
      const size_t so = (size_t)(t & 1) * 16384 + (size_t)sb * 512 + j0 + q * 4;
      __hip_atomic_store((u64*)(Hhi + so), vh, __ATOMIC_RELAXED, __HIP_MEMORY_SCOPE_AGENT);
      __hip_atomic_store((u64*)(Hlo + so), vo, __ATOMIC_RELAXED, __HIP_MEMORY_SCOPE_AGENT);
      asm volatile("s_waitcnt vmcnt(0)" ::: "memory");
      if (tid == 0)
        __hip_atomic_store(slots + (size_t)wg * 1024, (u32)(t + 1),
                           __ATOMIC_RELAXED, __HIP_MEMORY_SCOPE_AGENT);
    }
    // Deferred fused max-pool: overlaps the next poll. Visible to k_topic via
    // end-of-kernel release.
    if (id > 0 && hval > 0.f)
      atomicMax((int*)&mp[(size_t)(cb * 32 + (id - 1)) * 1024 + dir * 512 + (j0 + ciu)],
                __float_as_int(hval));
  }

  if (t1 < 512) Cb[cb * 512 + j0 + ciu] = c;   // spill c across phase boundary
}

// Fused dual-direction phase kernel: WGs 0..63 = dir0, 64..127 = dir1.
__global__ __launch_bounds__(256) void k_lstm2(
    const void* __restrict__ GA, const void* __restrict__ GB,
    const void* __restrict__ WhhA, const void* __restrict__ WhhB,
    u16* __restrict__ Hh0, u16* __restrict__ Hl0,
    u16* __restrict__ Hh1, u16* __restrict__ Hl1,
    float* __restrict__ Cb, float* __restrict__ mp,
    const void* __restrict__ uid, u32* __restrict__ slots,
    const u32* __restrict__ flags, int gHalf,
    int t0, int t1, int s0A, int s0B)
{
  const int dir = ((int)blockIdx.x >= 64) ? 1 : 0;
  const int wg = (int)blockIdx.x & 63;
  const void* Gv  = dir ? GB : GA;
  const void* Whh = dir ? WhhB : WhhA;
  u16* Hhi = dir ? Hh1 : Hh0;
  u16* Hlo = dir ? Hl1 : Hl0;
  lstm_body(wg, dir, t0, t1, dir ? s0B : s0A, Gv, Whh, Hhi, Hlo,
            Cb + (size_t)dir * 16384, mp, uid,
            slots + (size_t)dir * 65536, flags, gHalf);
}

// ---------------------------------------------------------------------------
// Phase 4a: topic_weights -> twT[k][t] fp32, bias -> fp32.
// ---------------------------------------------------------------------------
__global__ __launch_bounds__(256) void k_prep(
    const void* __restrict__ tw, const void* __restrict__ tb,
    float* __restrict__ twT, float* __restrict__ biasT, const u32* __restrict__ flags)
{
  const int isBF = (int)flags[0];
  const int idx = blockIdx.x * 256 + threadIdx.x;
  if (idx < 102400) {
    const int t = idx >> 10, k = idx & 1023;
    twT[k * 100 + t] = ldF(tw, idx, isBF);
  } else if (idx < 102500) {
    biasT[idx - 102400] = ldF(tb, idx - 102400, isBF);
  }
}

// ---------------------------------------------------------------------------
// Phase 4: per (b,u): logits(100) -> softmax -> emb row (fp32).
// ---------------------------------------------------------------------------
__global__ __launch_bounds__(256) void k_topic(
    const float* __restrict__ mp, const float* __restrict__ twT,
    const float* __restrict__ biasT, const void* __restrict__ table,
    float* __restrict__ emb, const u32* __restrict__ flags)
{
  const int isBF = (int)flags[0];
  const int bu = blockIdx.x;
  const int tid = threadIdx.x;
  __shared__ float lrow[1024];
  __shared__ float red[128];
  __shared__ float parr[128];
  for (int i = tid; i < 1024; i += 256) lrow[i] = mp[(size_t)bu * 1024 + i];
  __syncthreads();
  float lacc = -1e30f;
  if (tid < 100) {
    lacc = biasT[tid];
    for (int k = 0; k < 1024; ++k) lacc = fmaf(lrow[k], twT[k * 100 + tid], lacc);
  }
  if (tid < 128) red[tid] = (tid < 100) ? lacc : -1e30f;
  __syncthreads();
  for (int off = 64; off > 0; off >>= 1) {
    if (tid < off) red[tid] = fmaxf(red[tid], red[tid + off]);
    __syncthreads();
  }
  const float mxv = red[0];
  __syncthreads();
  const float e = (tid < 100) ? expf(lacc - mxv) : 0.f;
  if (tid < 128) red[tid] = e;
  __syncthreads();
  for (int off = 64; off > 0; off >>= 1) {
    if (tid < off) red[tid] += red[tid + off];
    __syncthreads();
  }
  const float inv = 1.f / red[0];
  if (tid < 128) parr[tid] = e * inv;
  __syncthreads();
#pragma unroll
  for (int r = 0; r < 4; ++r) {
    const int w = tid + 256 * r;
    float a = 0.f;
    for (int t = 0; t < 100; ++t)
      a = fmaf(parr[t], ldF(table, (size_t)t * 1024 + w, isBF), a);
    emb[(size_t)bu * 1024 + w] = a;
  }
}

// ---------------------------------------------------------------------------
// Phase 5: out = emb[b][clip(|uid|-1,0,31)][w] * {1,2,0}. Dtype by flag.
// ---------------------------------------------------------------------------
__global__ __launch_bounds__(256) void k_out(
    const float* __restrict__ emb, const void* __restrict__ uid,
    void* __restrict__ outv, const u32* __restrict__ flags)
{
  const int isBF = (int)flags[0];
  const int is64 = (int)flags[1];
  const int idx = blockIdx.x * 256 + threadIdx.x;
  const int w = idx & 1023;
  const int s = (idx >> 10) & 511;
  const int b = idx >> 19;
  const int id = ldI(uid, b * 512 + s, is64);
  const float wt = (id > 0) ? 1.f : ((id < 0) ? 2.f : 0.f);
  int au = (id < 0) ? (-id - 1) : (id - 1);
  au = max(0, min(31, au));
  const float v = emb[(size_t)(b * 32 + au) * 1024 + w] * wt;
  if (isBF) ((u16*)outv)[idx] = f2bf(v);
  else      ((float*)outv)[idx] = v;
}

// ---------------------------------------------------------------------------
// ws layout (phased fused dirs):
//  fp32-G (ws >= 143,934,464; R5 proved >=176.7MB):
//    GA 64Mi | GB 64Mi | Hh0,Hl0,Hh1,Hl1 4x64Ki | Cb 128Ki | mp 4Mi | emb 4Mi
//    | twT 400Ki | biasT 512 | slots 512Ki (128 x 4KB spread) | flags 512
//  fp16-G fallback: GA/GB 32Mi each + same tail ~= 76.8 MB
// ---------------------------------------------------------------------------
extern "C" void kernel_launch(void* const* d_in, const int* in_sizes, int n_in,
                              void* d_out, int out_size, void* d_ws, size_t ws_size,
                              hipStream_t stream) {
  (void)in_sizes; (void)n_in; (void)out_size;
  const void* X    = d_in[0];
  const void* uid  = d_in[1];
  const void* Wihf = d_in[2];
  const void* Whhf = d_in[3];
  const void* bihf = d_in[4];
  const void* bhhf = d_in[5];
  const void* Wihb = d_in[6];
  const void* Whhb = d_in[7];
  const void* bihb = d_in[8];
  const void* bhhb = d_in[9];
  const void* tw   = d_in[10];
  const void* tb   = d_in[11];
  const void* tt   = d_in[12];
  char* ws = (char*)d_ws;

  const int gHalf = (ws_size >= 143934464ull) ? 0 : 1;
  const size_t gB = gHalf ? 33554432ull : 67108864ull;   // per-dir G (256 steps)
  const size_t oGB = gB;
  const size_t oH  = 2ull * gB;
  const size_t oCb = oH + 262144ull;          // 4 slabs x 64Ki
  const size_t omp = oCb + 131072ull;
  const size_t oem = omp + 4194304ull;
  const size_t otw = oem + 4194304ull;
  const size_t obi = otw + 409600ull;
  const size_t osl = obi + 512ull;
  const size_t oFL = osl + 524288ull;

  void*  GA    = (void*)(ws + 0);
  void*  GB    = (void*)(ws + oGB);
  u16*   Hh0   = (u16*)(ws + oH);
  u16*   Hl0   = (u16*)(ws + oH + 65536ull);
  u16*   Hh1   = (u16*)(ws + oH + 131072ull);
  u16*   Hl1   = (u16*)(ws + oH + 196608ull);
  float* Cb    = (float*)(ws + oCb);
  float* mp    = (float*)(ws + omp);
  float* emb   = (float*)(ws + oem);
  float* twT   = (float*)(ws + otw);
  float* biasT = (float*)(ws + obi);
  u32*   slots = (u32*)(ws + osl);
  u32*   flags = (u32*)(ws + oFL);

  (void)hipMemsetAsync(mp, 0, 4194304ull, stream);    // segment-max floor = 0
  (void)hipMemsetAsync(slots, 0, 524288ull, stream);  // barrier slots (spread)
  k_probe<<<1, 256, 0, stream>>>((const u32*)X, (const u32*)uid, flags);

  // Phase A: dir0 s[0,256) -> GA; dir1 s[256,512) -> GB; steps t=0..255.
  k_xproj<<<dim3(128, 32), 256, 0, stream>>>(X, Wihf, bihf, bhhf, GA, flags, gHalf, 0);
  k_xproj<<<dim3(128, 32), 256, 0, stream>>>(X, Wihb, bihb, bhhb, GB, flags, gHalf, 256);
  k_lstm2<<<128, 256, 0, stream>>>(GA, GB, Whhf, Whhb, Hh0, Hl0, Hh1, Hl1,
                                   Cb, mp, uid, slots, flags, gHalf,
                                   0, 256, 0, 256);
  // Phase B: dir0 s[256,512) -> GA; dir1 s[0,256) -> GB; steps t=256..511.
  k_xproj<<<dim3(128, 32), 256, 0, stream>>>(X, Wihf, bihf, bhhf, GA, flags, gHalf, 256);
  k_xproj<<<dim3(128, 32), 256, 0, stream>>>(X, Wihb, bihb, bhhb, GB, flags, gHalf, 0);
  k_lstm2<<<128, 256, 0, stream>>>(GA, GB, Whhf, Whhb, Hh0, Hl0, Hh1, Hl1,
                                   Cb, mp, uid, slots, flags, gHalf,
                                   256, 512, 256, 0);

  k_prep<<<401, 256, 0, stream>>>(tw, tb, twT, biasT, flags);
  k_topic<<<1024, 256, 0, stream>>>(mp, twT, biasT, tt, emb, flags);
  k_out<<<65536, 256, 0, stream>>>(emb, uid, d_out, flags);
}

// Round 9
// 4516.825 us; speedup vs baseline: 4.4607x; 1.2812x over previous
//
#include <hip/hip_runtime.h>
#include <hip/hip_fp16.h>

// GetTopic: biLSTM (B=32,S=512,W=1024,HP=512) -> fused per-utterance segment
// max -> topic softmax (T=100) -> weighted gather. Inputs fp32 (probe kept).
//
// R15 = R14 (5.79 ms, PROVEN) + ONE delta in lstm_body: the A-operand h
// loads (previously 256 thr x 512 B scattered sc1 = 128 KB/WG/step, 2x
// redundant across nt-waves -> 16 MB/step fabric burst) are replaced by a
// cooperative coalesced LDS stage: 64 KB unique (Hhi+Hlo) loaded once per
// WG (16B/lane runs, sc1), XOR-swizzled into LDS (byte ^= ((row&7)<<4) on
// write AND read -> 2-way banks, free), fragments then ds_read_b128.
// Halves MALL traffic and removes address scatter from the critical path.
// Everything else verbatim R14: phased dual-dir k_lstm2, MFMA xproj,
// slot barrier (4KB spread), LDS-staged wave0 h stores, deferred atomicMax.

typedef unsigned short u16;
typedef unsigned int   u32;
typedef unsigned long long u64;
typedef __attribute__((ext_vector_type(8))) short short8;
typedef __attribute__((ext_vector_type(4))) float float4v;

__device__ __forceinline__ float bf2f(u16 u) { return __uint_as_float(((u32)u) << 16); }
__device__ __forceinline__ u16 f2bf(float f) {
  u32 u = __float_as_uint(f);
  u32 r = u + 0x7FFFu + ((u >> 16) & 1u);   // RNE
  return (u16)(r >> 16);
}
__device__ __forceinline__ float sigm(float x) { return 1.f / (1.f + expf(-x)); }

__device__ __forceinline__ float ldF(const void* p, size_t i, int isBF) {
  return isBF ? bf2f(((const u16*)p)[i]) : ((const float*)p)[i];
}
__device__ __forceinline__ int ldI(const void* p, int i, int is64) {
  return is64 ? (int)((const u32*)p)[(size_t)2 * i] : ((const int*)p)[i];
}

union U4S8 { uint4 u; short8 s; u16 us[8]; };

// ---------------------------------------------------------------------------
// Probe: input storage formats from raw bits (R4/R5-proven).
// flags[0]: 1 = float tensors bf16, 0 = fp32.  flags[1]: 1 = ids int64.
// ---------------------------------------------------------------------------
__global__ __launch_bounds__(256) void k_probe(
    const u32* __restrict__ X, const u32* __restrict__ U, u32* __restrict__ flags)
{
  __shared__ int cnt[2];
  if (threadIdx.x == 0) { cnt[0] = 0; cnt[1] = 0; }
  __syncthreads();
  int c0 = 0;
  for (int i = threadIdx.x; i < 1024; i += 256) {
    const u32 e = (X[i] >> 7) & 0xFFu;
    if (e >= 112u && e <= 143u) c0++;
  }
  int c1 = 0;
  {
    const u32 w = U[2 * threadIdx.x + 1];
    if (w == 0u || w == 0xFFFFFFFFu) c1++;
  }
  atomicAdd(&cnt[0], c0);
  atomicAdd(&cnt[1], c1);
  __syncthreads();
  if (threadIdx.x == 0) {
    flags[0] = (cnt[0] >= 512) ? 1u : 0u;
    flags[1] = (cnt[1] >= 128) ? 1u : 0u;
  }
}

// ---------------------------------------------------------------------------
// Phase 1: G_local[sl][n][b] = x[s0+sl] @ Wih^T + (bih+bhh) for sl in [0,256).
// R14-proven: split-bf16 MFMA GEMM. M=8192 (m=sl*32+b), N=2048, K=1024.
// ---------------------------------------------------------------------------
__global__ __launch_bounds__(256) void k_xproj(
    const void* __restrict__ X, const void* __restrict__ Wih,
    const void* __restrict__ bih, const void* __restrict__ bhh,
    void* __restrict__ Gv, const u32* __restrict__ flags, int gHalf, int s0)
{
  const int isBF = (int)flags[0];
  const int m0 = blockIdx.x * 64;
  const int n0 = blockIdx.y * 64;
  __shared__ u16 Ah[64][40];   // stride 40 u16 (80B)
  __shared__ u16 Al[64][40];
  __shared__ u16 Bh[64][40];
  __shared__ u16 Bl[64][40];
  const int tid = threadIdx.x;
  const int lrow = tid >> 2;          // 0..63: staging row
  const int lkg  = (tid & 3) * 8;     // k-group of 8 within 32-wide k-tile
  const int lane = tid & 63;
  const int wid  = tid >> 6;          // wave -> M-chunk
  const int l15  = lane & 15;
  const int quad = lane >> 4;
  const int am = m0 + lrow;
  const int ab = am & 31, asl = am >> 5;           // m = sl*32 + b
  const size_t arow = ((size_t)ab * 512 + (s0 + asl)) * 1024;
  const size_t brow = (size_t)(n0 + lrow) * 1024;

  float4v acc[4];
#pragma unroll
  for (int c = 0; c < 4; ++c) {
    acc[c].x = 0.f; acc[c].y = 0.f; acc[c].z = 0.f; acc[c].w = 0.f;
  }

  for (int k0 = 0; k0 < 1024; k0 += 32) {
    float a8[8], b8[8];
    if (isBF) {
      const u16* Xh = (const u16*)X;
      const u16* Wh = (const u16*)Wih;
      uint4 va = *(const uint4*)(Xh + arow + k0 + lkg);
      uint4 vb = *(const uint4*)(Wh + brow + k0 + lkg);
      const u32 wa[4] = {va.x, va.y, va.z, va.w};
      const u32 wb[4] = {vb.x, vb.y, vb.z, vb.w};
#pragma unroll
      for (int q = 0; q < 4; ++q) {
        a8[2 * q]     = __uint_as_float(wa[q] << 16);
        a8[2 * q + 1] = __uint_as_float(wa[q] & 0xFFFF0000u);
        b8[2 * q]     = __uint_as_float(wb[q] << 16);
        b8[2 * q + 1] = __uint_as_float(wb[q] & 0xFFFF0000u);
      }
    } else {
      const float* Xf = (const float*)X;
      const float* Wf = (const float*)Wih;
      const float4 xa0 = *(const float4*)(Xf + arow + k0 + lkg);
      const float4 xa1 = *(const float4*)(Xf + arow + k0 + lkg + 4);
      const float4 xb0 = *(const float4*)(Wf + brow + k0 + lkg);
      const float4 xb1 = *(const float4*)(Wf + brow + k0 + lkg + 4);
      a8[0] = xa0.x; a8[1] = xa0.y; a8[2] = xa0.z; a8[3] = xa0.w;
      a8[4] = xa1.x; a8[5] = xa1.y; a8[6] = xa1.z; a8[7] = xa1.w;
      b8[0] = xb0.x; b8[1] = xb0.y; b8[2] = xb0.z; b8[3] = xb0.w;
      b8[4] = xb1.x; b8[5] = xb1.y; b8[6] = xb1.z; b8[7] = xb1.w;
    }
    U4S8 pah, pal, pbh, pbl;
#pragma unroll
    for (int j = 0; j < 8; ++j) {
      const u16 ah = f2bf(a8[j]);
      pah.us[j] = ah; pal.us[j] = f2bf(a8[j] - bf2f(ah));
      const u16 bh = f2bf(b8[j]);
      pbh.us[j] = bh; pbl.us[j] = f2bf(b8[j] - bf2f(bh));
    }
    *(uint4*)&Ah[lrow][lkg] = pah.u;
    *(uint4*)&Al[lrow][lkg] = pal.u;
    *(uint4*)&Bh[lrow][lkg] = pbh.u;
    *(uint4*)&Bl[lrow][lkg] = pbl.u;
    __syncthreads();

    U4S8 fah, fal;
    fah.u = *(const uint4*)&Ah[wid * 16 + l15][quad * 8];
    fal.u = *(const uint4*)&Al[wid * 16 + l15][quad * 8];
#pragma unroll
    for (int c = 0; c < 4; ++c) {
      U4S8 fbh, fbl;
      fbh.u = *(const uint4*)&Bh[c * 16 + l15][quad * 8];
      fbl.u = *(const uint4*)&Bl[c * 16 + l15][quad * 8];
      acc[c] = __builtin_amdgcn_mfma_f32_16x16x32_bf16(fah.s, fbh.s, acc[c], 0, 0, 0);
      acc[c] = __builtin_amdgcn_mfma_f32_16x16x32_bf16(fah.s, fbl.s, acc[c], 0, 0, 0);
      acc[c] = __builtin_amdgcn_mfma_f32_16x16x32_bf16(fal.s, fbh.s, acc[c], 0, 0, 0);
    }
    __syncthreads();
  }

  const int mrow = m0 + wid * 16 + quad * 4;
  const int b0 = mrow & 31, sl = mrow >> 5;
#pragma unroll
  for (int c = 0; c < 4; ++c) {
    const int n = n0 + c * 16 + l15;
    const float bias = ldF(bih, n, isBF) + ldF(bhh, n, isBF);
    const size_t off = ((size_t)sl * 2048 + n) * 32 + b0;
    if (gHalf) {
      ushort4 pk;
      pk.x = __half_as_ushort(__float2half(acc[c].x + bias));
      pk.y = __half_as_ushort(__float2half(acc[c].y + bias));
      pk.z = __half_as_ushort(__float2half(acc[c].z + bias));
      pk.w = __half_as_ushort(__float2half(acc[c].w + bias));
      *(uint2*)((u16*)Gv + off) = *(uint2*)&pk;
    } else {
      float4 pk;
      pk.x = acc[c].x + bias; pk.y = acc[c].y + bias;
      pk.z = acc[c].z + bias; pk.w = acc[c].w + bias;
      *(float4*)((float*)Gv + off) = pk;
    }
  }
}

// ---------------------------------------------------------------------------
// Phase 2 body. One dir, 64 WGs x 256. WG owns 8 hidden units = 32 gate
// cols; Whh resident as split-bf16 MFMA fragments (3 chains ~ fp32).
// R15: prev-step h slabs (Hhi+Hlo, 64 KB) cooperatively staged into
// XOR-swizzled LDS once per step; A-fragments ds_read from LDS.
// ---------------------------------------------------------------------------
__device__ __forceinline__ void lstm_body(
    const int wg, const int dir, const int t0, const int t1, const int s0,
    const void* __restrict__ Gv, const void* __restrict__ Whh,
    u16* __restrict__ Hhi, u16* __restrict__ Hlo, float* __restrict__ Cb,
    float* __restrict__ mp, const void* __restrict__ uid,
    u32* __restrict__ slots, const u32* __restrict__ flags, const int gHalf)
{
  __shared__ float gl[1024];                    // [col32][b32] gate preacts
  __shared__ __align__(16) u16 shh[256];        // staged h hi: [b32][u8]
  __shared__ __align__(16) u16 shl[256];        // staged h lo: [b32][u8]
  __shared__ __align__(16) u16 HhS[16384];      // 32 KB swizzled h-hi slab
  __shared__ __align__(16) u16 HlS[16384];      // 32 KB swizzled h-lo slab
  const int isBF = (int)flags[0];
  const int is64 = (int)flags[1];
  const int tid = threadIdx.x;
  const int j0 = wg * 8;
  const int lane = tid & 63;
  const int wid = tid >> 6;
  const int mt = wid & 1, nt = wid >> 1;
  const int l15 = lane & 15;
  const int quad = lane >> 4;
  const int nl = nt * 16 + l15;        // col 0..31 within WG
  const int n = ((nl >> 3) * 512) + j0 + (nl & 7);   // global gate row/col

  // B-frags: split-bf16 of Whh row n. B[n=l15][k=quad*8+j].
  short8 bhi[16], blo[16];
#pragma unroll 1
  for (int kt = 0; kt < 16; ++kt) {
    const int k0 = kt * 32 + quad * 8;
    float w[8];
    if (isBF) {
      const u16* Wh = (const u16*)Whh;
#pragma unroll
      for (int jj = 0; jj < 8; ++jj) w[jj] = bf2f(Wh[(size_t)n * 512 + k0 + jj]);
    } else {
      const float* Wf = (const float*)Whh;
      const float4 w0 = *(const float4*)(Wf + (size_t)n * 512 + k0);
      const float4 w1 = *(const float4*)(Wf + (size_t)n * 512 + k0 + 4);
      w[0] = w0.x; w[1] = w0.y; w[2] = w0.z; w[3] = w0.w;
      w[4] = w1.x; w[5] = w1.y; w[6] = w1.z; w[7] = w1.w;
    }
    U4S8 ph, pl;
#pragma unroll
    for (int jj = 0; jj < 8; ++jj) {
      const u16 hi = f2bf(w[jj]);
      const float rem = w[jj] - bf2f(hi);   // exact (Sterbenz)
      ph.us[jj] = hi; pl.us[jj] = f2bf(rem);
    }
    bhi[kt] = ph.s; blo[kt] = pl.s;
  }

  const int b_a = mt * 16 + l15;        // A row = batch
  const int cb = tid & 31;              // consumer: batch
  const int ciu = tid >> 5;             // consumer: unit 0..7
  float c = (t0 == 0) ? 0.f : Cb[cb * 512 + j0 + ciu];

  // Per-thread G column offset; per-step local offset = ls*65536 + gcol.
  const size_t gcol = (size_t)n * 32 + (size_t)(mt * 16 + quad * 4);

  // Prefetch G for t=t0 (plain cached loads -- L2 stays warm).
  float4v gpre;
  {
    const int ls = dir ? (511 - t0 - s0) : (t0 - s0);
    const size_t goff = (size_t)ls * 65536 + gcol;
    if (gHalf) {
      const __half* Gp = (const __half*)Gv;
      gpre.x = __half2float(Gp[goff + 0]);
      gpre.y = __half2float(Gp[goff + 1]);
      gpre.z = __half2float(Gp[goff + 2]);
      gpre.w = __half2float(Gp[goff + 3]);
    } else {
      const float4 gv = *(const float4*)((const float*)Gv + goff);
      gpre.x = gv.x; gpre.y = gv.y; gpre.z = gv.z; gpre.w = gv.w;
    }
  }

  // A-fragment LDS byte offset (swizzled): row b_a, col byte kt*64+quad*16.
  const int abase_sw = b_a * 1024;
  const int aswz = (b_a & 7) << 4;

  for (int t = t0; t < t1; ++t) {
    const int sidx = dir ? (511 - t) : t;
    if (t > t0) {
      // Parallel detection: lane i of wave 0 polls slot i (4KB spread).
      if (tid < 64) {
        const u32 target = (u32)t;
        const u32* sl = slots + (size_t)lane * 1024;   // 4KB stride
        for (;;) {
          const u32 v = __hip_atomic_load(sl, __ATOMIC_RELAXED, __HIP_MEMORY_SCOPE_AGENT);
          if (__all((int)(v >= target))) break;
          __builtin_amdgcn_s_sleep(1);
        }
      }
      __syncthreads();
    }

    // C-init from prefetched G (4 consecutive batches per lane, col n).
    float4v acc_hh = gpre;
    float4v acc_hl, acc_lh;
    acc_hl.x = 0.f; acc_hl.y = 0.f; acc_hl.z = 0.f; acc_hl.w = 0.f;
    acc_lh.x = 0.f; acc_lh.y = 0.f; acc_lh.z = 0.f; acc_lh.w = 0.f;

    if (t > 0) {
      // Cooperative coalesced stage of prev-step h slabs into LDS.
      // Thread loads bytes [tid*16 + j*4096) of each 32 KB slab (16B/lane
      // contiguous runs), sc1 (MALL-coherent); writes LDS with the read
      // swizzle byte ^= ((row&7)<<4), row = byte>>10.
      const u16* sbh = Hhi + (size_t)((t - 1) & 1) * 16384;
      const u16* sbl = Hlo + (size_t)((t - 1) & 1) * 16384;
      uint4 th[8], tl[8];
#pragma unroll
      for (int j = 0; j < 8; ++j) {
        const u16* ph = sbh + tid * 8 + j * 2048;
        const u16* pl = sbl + tid * 8 + j * 2048;
        asm volatile(
            "global_load_dwordx4 %0, %2, off sc1\n\t"
            "global_load_dwordx4 %1, %3, off sc1"
            : "=v"(th[j]), "=v"(tl[j])
            : "v"(ph), "v"(pl)
            : "memory");
      }
      asm volatile("s_waitcnt vmcnt(0)" ::: "memory");
      __builtin_amdgcn_sched_barrier(0);
#pragma unroll
      for (int j = 0; j < 8; ++j) {
        const int L = tid * 16 + j * 4096;
        const int a = L ^ (((L >> 10) & 7) << 4);
        *(uint4*)((char*)HhS + a) = th[j];
        *(uint4*)((char*)HlS + a) = tl[j];
      }
      __syncthreads();

#pragma unroll
      for (int kt = 0; kt < 16; ++kt) {
        const int aoff = (abase_sw + kt * 64 + quad * 16) ^ aswz;
        U4S8 va, vl;
        va.u = *(const uint4*)((const char*)HhS + aoff);
        vl.u = *(const uint4*)((const char*)HlS + aoff);
        acc_hh = __builtin_amdgcn_mfma_f32_16x16x32_bf16(va.s, bhi[kt], acc_hh, 0, 0, 0);
        acc_hl = __builtin_amdgcn_mfma_f32_16x16x32_bf16(va.s, blo[kt], acc_hl, 0, 0, 0);
        acc_lh = __builtin_amdgcn_mfma_f32_16x16x32_bf16(vl.s, bhi[kt], acc_lh, 0, 0, 0);
      }
    }

    // Prefetch next step's G (independent; hides under exchange + barrier).
    if (t + 1 < t1) {
      const int ls = dir ? (511 - (t + 1) - s0) : (t + 1 - s0);
      const size_t goff = (size_t)ls * 65536 + gcol;
      if (gHalf) {
        const __half* Gp = (const __half*)Gv;
        gpre.x = __half2float(Gp[goff + 0]);
        gpre.y = __half2float(Gp[goff + 1]);
        gpre.z = __half2float(Gp[goff + 2]);
        gpre.w = __half2float(Gp[goff + 3]);
      } else {
        const float4 gv = *(const float4*)((const float*)Gv + goff);
        gpre.x = gv.x; gpre.y = gv.y; gpre.z = gv.z; gpre.w = gv.w;
      }
    }

    // exchange: D row (quad*4+r) = batch - mt*16, col l15 -> nl
    {
      const int base = nl * 32 + mt * 16 + quad * 4;
      gl[base + 0] = acc_hh.x + acc_hl.x + acc_lh.x;
      gl[base + 1] = acc_hh.y + acc_hl.y + acc_lh.y;
      gl[base + 2] = acc_hh.z + acc_hl.z + acc_lh.z;
      gl[base + 3] = acc_hh.w + acc_hl.w + acc_lh.w;
    }
    __syncthreads();

    float hval;
    int id;
    {
      const float a0 = gl[(0 * 8 + ciu) * 32 + cb];
      const float a1 = gl[(1 * 8 + ciu) * 32 + cb];
      const float a2 = gl[(2 * 8 + ciu) * 32 + cb];
      const float a3 = gl[(3 * 8 + ciu) * 32 + cb];
      const float ig = sigm(a0), fg = sigm(a1);
      const float gg = tanhf(a2), og = sigm(a3);
      c = fg * c + ig * gg;
      hval = og * tanhf(c);
      const u16 hh = f2bf(hval);
      shh[cb * 8 + ciu] = hh;
      shl[cb * 8 + ciu] = f2bf(hval - bf2f(hh));
      id = ldI(uid, cb * 512 + sidx, is64);
    }
    __syncthreads();

    // Wave 0: re-gather staged h, 128x 8B agent stores (16B runs per batch),
    // one drain, tid0 publishes. Other waves proceed to atomicMax.
    if (tid < 64) {
      const int sb = lane >> 1, q = lane & 1;       // batch, 4-unit chunk
      const u64 vh = ((const u64*)shh)[sb * 2 + q];
      const u64 vo = ((const u64*)shl)[sb * 2 + q];
      const size_t so = (size_t)(t & 1) * 16384 + (size_t)sb * 512 + j0 + q * 4;
      __hip_atomic_store((u64*)(Hhi + so), vh, __ATOMIC_RELAXED, __HIP_MEMORY_SCOPE_AGENT);
      __hip_atomic_store((u64*)(Hlo + so), vo, __ATOMIC_RELAXED, __HIP_MEMORY_SCOPE_AGENT);
      asm volatile("s_waitcnt vmcnt(0)" ::: "memory");
      if (tid == 0)
        __hip_atomic_store(slots + (size_t)wg * 1024, (u32)(t + 1),
                           __ATOMIC_RELAXED, __HIP_MEMORY_SCOPE_AGENT);
    }
    // Deferred fused max-pool: overlaps the next poll.
    if (id > 0 && hval > 0.f)
      atomicMax((int*)&mp[(size_t)(cb * 32 + (id - 1)) * 1024 + dir * 512 + (j0 + ciu)],
                __float_as_int(hval));
  }

  if (t1 < 512) Cb[cb * 512 + j0 + ciu] = c;   // spill c across phase boundary
}

// Fused dual-direction phase kernel: WGs 0..63 = dir0, 64..127 = dir1.
__global__ __launch_bounds__(256) void k_lstm2(
    const void* __restrict__ GA, const void* __restrict__ GB,
    const void* __restrict__ WhhA, const void* __restrict__ WhhB,
    u16* __restrict__ Hh0, u16* __restrict__ Hl0,
    u16* __restrict__ Hh1, u16* __restrict__ Hl1,
    float* __restrict__ Cb, float* __restrict__ mp,
    const void* __restrict__ uid, u32* __restrict__ slots,
    const u32* __restrict__ flags, int gHalf,
    int t0, int t1, int s0A, int s0B)
{
  const int dir = ((int)blockIdx.x >= 64) ? 1 : 0;
  const int wg = (int)blockIdx.x & 63;
  const void* Gv  = dir ? GB : GA;
  const void* Whh = dir ? WhhB : WhhA;
  u16* Hhi = dir ? Hh1 : Hh0;
  u16* Hlo = dir ? Hl1 : Hl0;
  lstm_body(wg, dir, t0, t1, dir ? s0B : s0A, Gv, Whh, Hhi, Hlo,
            Cb + (size_t)dir * 16384, mp, uid,
            slots + (size_t)dir * 65536, flags, gHalf);
}

// ---------------------------------------------------------------------------
// Phase 4a: topic_weights -> twT[k][t] fp32, bias -> fp32.
// ---------------------------------------------------------------------------
__global__ __launch_bounds__(256) void k_prep(
    const void* __restrict__ tw, const void* __restrict__ tb,
    float* __restrict__ twT, float* __restrict__ biasT, const u32* __restrict__ flags)
{
  const int isBF = (int)flags[0];
  const int idx = blockIdx.x * 256 + threadIdx.x;
  if (idx < 102400) {
    const int t = idx >> 10, k = idx & 1023;
    twT[k * 100 + t] = ldF(tw, idx, isBF);
  } else if (idx < 102500) {
    biasT[idx - 102400] = ldF(tb, idx - 102400, isBF);
  }
}

// ---------------------------------------------------------------------------
// Phase 4: per (b,u): logits(100) -> softmax -> emb row (fp32).
// ---------------------------------------------------------------------------
__global__ __launch_bounds__(256) void k_topic(
    const float* __restrict__ mp, const float* __restrict__ twT,
    const float* __restrict__ biasT, const void* __restrict__ table,
    float* __restrict__ emb, const u32* __restrict__ flags)
{
  const int isBF = (int)flags[0];
  const int bu = blockIdx.x;
  const int tid = threadIdx.x;
  __shared__ float lrow[1024];
  __shared__ float red[128];
  __shared__ float parr[128];
  for (int i = tid; i < 1024; i += 256) lrow[i] = mp[(size_t)bu * 1024 + i];
  __syncthreads();
  float lacc = -1e30f;
  if (tid < 100) {
    lacc = biasT[tid];
    for (int k = 0; k < 1024; ++k) lacc = fmaf(lrow[k], twT[k * 100 + tid], lacc);
  }
  if (tid < 128) red[tid] = (tid < 100) ? lacc : -1e30f;
  __syncthreads();
  for (int off = 64; off > 0; off >>= 1) {
    if (tid < off) red[tid] = fmaxf(red[tid], red[tid + off]);
    __syncthreads();
  }
  const float mxv = red[0];
  __syncthreads();
  const float e = (tid < 100) ? expf(lacc - mxv) : 0.f;
  if (tid < 128) red[tid] = e;
  __syncthreads();
  for (int off = 64; off > 0; off >>= 1) {
    if (tid < off) red[tid] += red[tid + off];
    __syncthreads();
  }
  const float inv = 1.f / red[0];
  if (tid < 128) parr[tid] = e * inv;
  __syncthreads();
#pragma unroll
  for (int r = 0; r < 4; ++r) {
    const int w = tid + 256 * r;
    float a = 0.f;
    for (int t = 0; t < 100; ++t)
      a = fmaf(parr[t], ldF(table, (size_t)t * 1024 + w, isBF), a);
    emb[(size_t)bu * 1024 + w] = a;
  }
}

// ---------------------------------------------------------------------------
// Phase 5: out = emb[b][clip(|uid|-1,0,31)][w] * {1,2,0}. Dtype by flag.
// ---------------------------------------------------------------------------
__global__ __launch_bounds__(256) void k_out(
    const float* __restrict__ emb, const void* __restrict__ uid,
    void* __restrict__ outv, const u32* __restrict__ flags)
{
  const int isBF = (int)flags[0];
  const int is64 = (int)flags[1];
  const int idx = blockIdx.x * 256 + threadIdx.x;
  const int w = idx & 1023;
  const int s = (idx >> 10) & 511;
  const int b = idx >> 19;
  const int id = ldI(uid, b * 512 + s, is64);
  const float wt = (id > 0) ? 1.f : ((id < 0) ? 2.f : 0.f);
  int au = (id < 0) ? (-id - 1) : (id - 1);
  au = max(0, min(31, au));
  const float v = emb[(size_t)(b * 32 + au) * 1024 + w] * wt;
  if (isBF) ((u16*)outv)[idx] = f2bf(v);
  else      ((float*)outv)[idx] = v;
}

// ---------------------------------------------------------------------------
// ws layout (phased fused dirs):
//  fp32-G (ws >= 143,934,464; R5 proved >=176.7MB):
//    GA 64Mi | GB 64Mi | Hh0,Hl0,Hh1,Hl1 4x64Ki | Cb 128Ki | mp 4Mi | emb 4Mi
//    | twT 400Ki | biasT 512 | slots 512Ki (128 x 4KB spread) | flags 512
//  fp16-G fallback: GA/GB 32Mi each + same tail ~= 76.8 MB
// ---------------------------------------------------------------------------
extern "C" void kernel_launch(void* const* d_in, const int* in_sizes, int n_in,
                              void* d_out, int out_size, void* d_ws, size_t ws_size,
                              hipStream_t stream) {
  (void)in_sizes; (void)n_in; (void)out_size;
  const void* X    = d_in[0];
  const void* uid  = d_in[1];
  const void* Wihf = d_in[2];
  const void* Whhf = d_in[3];
  const void* bihf = d_in[4];
  const void* bhhf = d_in[5];
  const void* Wihb = d_in[6];
  const void* Whhb = d_in[7];
  const void* bihb = d_in[8];
  const void* bhhb = d_in[9];
  const void* tw   = d_in[10];
  const void* tb   = d_in[11];
  const void* tt   = d_in[12];
  char* ws = (char*)d_ws;

  const int gHalf = (ws_size >= 143934464ull) ? 0 : 1;
  const size_t gB = gHalf ? 33554432ull : 67108864ull;   // per-dir G (256 steps)
  const size_t oGB = gB;
  const size_t oH  = 2ull * gB;
  const size_t oCb = oH + 262144ull;          // 4 slabs x 64Ki
  const size_t omp = oCb + 131072ull;
  const size_t oem = omp + 4194304ull;
  const size_t otw = oem + 4194304ull;
  const size_t obi = otw + 409600ull;
  const size_t osl = obi + 512ull;
  const size_t oFL = osl + 524288ull;

  void*  GA    = (void*)(ws + 0);
  void*  GB    = (void*)(ws + oGB);
  u16*   Hh0   = (u16*)(ws + oH);
  u16*   Hl0   = (u16*)(ws + oH + 65536ull);
  u16*   Hh1   = (u16*)(ws + oH + 131072ull);
  u16*   Hl1   = (u16*)(ws + oH + 196608ull);
  float* Cb    = (float*)(ws + oCb);
  float* mp    = (float*)(ws + omp);
  float* emb   = (float*)(ws + oem);
  float* twT   = (float*)(ws + otw);
  float* biasT = (float*)(ws + obi);
  u32*   slots = (u32*)(ws + osl);
  u32*   flags = (u32*)(ws + oFL);

  (void)hipMemsetAsync(mp, 0, 4194304ull, stream);    // segment-max floor = 0
  (void)hipMemsetAsync(slots, 0, 524288ull, stream);  // barrier slots (spread)
  k_probe<<<1, 256, 0, stream>>>((const u32*)X, (const u32*)uid, flags);

  // Phase A: dir0 s[0,256) -> GA; dir1 s[256,512) -> GB; steps t=0..255.
  k_xproj<<<dim3(128, 32), 256, 0, stream>>>(X, Wihf, bihf, bhhf, GA, flags, gHalf, 0);
  k_xproj<<<dim3(128, 32), 256, 0, stream>>>(X, Wihb, bihb, bhhb, GB, flags, gHalf, 256);
  k_lstm2<<<128, 256, 0, stream>>>(GA, GB, Whhf, Whhb, Hh0, Hl0, Hh1, Hl1,
                                   Cb, mp, uid, slots, flags, gHalf,
                                   0, 256, 0, 256);
  // Phase B: dir0 s[256,512) -> GA; dir1 s[0,256) -> GB; steps t=256..511.
  k_xproj<<<dim3(128, 32), 256, 0, stream>>>(X, Wihf, bihf, bhhf, GA, flags, gHalf, 256);
  k_xproj<<<dim3(128, 32), 256, 0, stream>>>(X, Wihb, bihb, bhhb, GB, flags, gHalf, 0);
  k_lstm2<<<128, 256, 0, stream>>>(GA, GB, Whhf, Whhb, Hh0, Hl0, Hh1, Hl1,
                                   Cb, mp, uid, slots, flags, gHalf,
                                   256, 512, 256, 0);

  k_prep<<<401, 256, 0, stream>>>(tw, tb, twT, biasT, flags);
  k_topic<<<1024, 256, 0, stream>>>(mp, twT, biasT, tt, emb, flags);
  k_out<<<65536, 256, 0, stream>>>(emb, uid, d_out, flags);
}